// Round 2
// baseline (1296.411 us; speedup 1.0000x reference)
//
#include <hip/hip_runtime.h>
#include <hip/hip_bf16.h>
#include <stdint.h>

typedef unsigned short u16;
typedef __bf16 bf16x8 __attribute__((ext_vector_type(8)));
typedef unsigned short u16x8 __attribute__((ext_vector_type(8)));
typedef float f32x4 __attribute__((ext_vector_type(4)));

__device__ __forceinline__ float bf2f(u16 u){ union{float f; unsigned i;} v; v.i = ((unsigned)u)<<16; return v.f; }
__device__ __forceinline__ u16 f2bf(float f){ union{float f; unsigned i;} v; v.f=f; unsigned r = v.i + 0x7FFFu + ((v.i>>16)&1u); return (u16)(r>>16); }

__device__ __forceinline__ void async16(const void* g, void* l){
  __builtin_amdgcn_global_load_lds((const __attribute__((address_space(1))) void*)g,
                                   (__attribute__((address_space(3))) void*)l, 16, 0, 0);
}

// ---------------- f32 -> bf16 elementwise cast (vectorized) ----------------
__global__ __launch_bounds__(256) void cvt_f2b(const float* __restrict__ src, u16* __restrict__ dst, int n)
{
  int i = (blockIdx.x * 256 + threadIdx.x) * 4;
  if (i < n) {
    float4 v = *(const float4*)&src[i];
    ushort4 o;
    o.x = f2bf(v.x); o.y = f2bf(v.y); o.z = f2bf(v.z); o.w = f2bf(v.w);
    *(ushort4*)&dst[i] = o;
  }
}

// ---------------- f32 src -> bf16 transposed dst, 64x64 tiles ----------------
// dst[c][r] = (bf16)src[r][c]
__global__ __launch_bounds__(256) void transpose2d_f2b(const float* __restrict__ src, u16* __restrict__ dst,
                                                       int src_rows, int src_cols)
{
  __shared__ u16 tile[64][72];
  const int r0 = blockIdx.y << 6, c0 = blockIdx.x << 6;
  const int t = threadIdx.x;
  #pragma unroll
  for (int i=0;i<4;i++){
    int slot = t + (i<<8);                     // 0..1023
    int r = slot >> 4, cv = (slot & 15) << 2;  // 4-elem granules
    float4 v = *(const float4*)&src[(size_t)(r0+r)*src_cols + c0 + cv];
    tile[r][cv+0] = f2bf(v.x); tile[r][cv+1] = f2bf(v.y);
    tile[r][cv+2] = f2bf(v.z); tile[r][cv+3] = f2bf(v.w);
  }
  __syncthreads();
  #pragma unroll
  for (int i=0;i<2;i++){
    int slot = t + (i<<8);
    int cr = slot >> 3, rv = (slot & 7) << 3;
    u16x8 v;
    #pragma unroll
    for (int e=0;e<8;e++) v[e] = tile[rv+e][cr];
    *(u16x8*)&dst[(size_t)(c0+cr)*src_rows + r0 + rv] = v;
  }
}

// ---------------- V transpose: qkv[b,t, 2*2048 + h*128 + d] -> vt[bh][d][t] (bf16) ----------------
__global__ __launch_bounds__(256) void transpose_v(const u16* __restrict__ qkv, u16* __restrict__ vt)
{
  __shared__ u16 tile[64][72];
  const int bh = blockIdx.z;
  const int b = bh >> 4, h = bh & 15;
  const u16* src = qkv + (size_t)b*2048*6144 + 4096 + h*128;   // [t][d], row stride 6144
  u16* dst = vt + (size_t)bh*128*2048;                          // [d][t], row stride 2048
  const int t0 = blockIdx.y << 6, d0 = blockIdx.x << 6;
  const int t = threadIdx.x;
  #pragma unroll
  for (int i=0;i<2;i++){
    int slot = t + (i<<8);
    int r = slot >> 3, cv = (slot & 7) << 3;
    *(u16x8*)&tile[r][cv] = *(const u16x8*)&src[(size_t)(t0+r)*6144 + d0 + cv];
  }
  __syncthreads();
  #pragma unroll
  for (int i=0;i<2;i++){
    int slot = t + (i<<8);
    int cr = slot >> 3, rv = (slot & 7) << 3;
    u16x8 v;
    #pragma unroll
    for (int e=0;e<8;e++) v[e] = tile[rv+e][cr];
    *(u16x8*)&dst[(size_t)(d0+cr)*2048 + t0 + rv] = v;
  }
}

// ---------------- GEMM C = A * Bt^T + bias (bf16 in, f32 accum) ----------------
// A: [M][K] bf16 row-major, Bt: [N][K] bf16 row-major, bias: f32[N]
// C: bf16 [M][N] if !F32OUT, else f32 [M][N]
template<int F32OUT>
__global__ __launch_bounds__(256) void gemm_bt(const u16* __restrict__ A, const u16* __restrict__ Bt,
                                               const float* __restrict__ bias, void* __restrict__ Cv,
                                               int M, int N, int K)
{
  __shared__ u16 lsA[128*32];
  __shared__ u16 lsB[128*32];
  const int tid = threadIdx.x;
  const int w = tid >> 6, lane = tid & 63;
  const int wm = w >> 1, wn = w & 1;
  const int m0 = blockIdx.y << 7, n0 = blockIdx.x << 7;
  const int lo = lane & 15, hi = lane >> 4;

  f32x4 acc[4][4];
  f32x4 z = {0.f,0.f,0.f,0.f};
  #pragma unroll
  for (int i=0;i<4;i++)
    #pragma unroll
    for (int j=0;j<4;j++) acc[i][j] = z;

  const int rA = lane >> 2;          // row within 16-row chunk
  const int cA = (lane & 3) << 3;    // 0,8,16,24

  for (int k0 = 0; k0 < K; k0 += 32) {
    #pragma unroll
    for (int i=0;i<2;i++){
      int chunk = w + (i<<2);
      async16(A  + (size_t)(m0 + chunk*16 + rA)*K + k0 + cA, &lsA[chunk*512]);
      async16(Bt + (size_t)(n0 + chunk*16 + rA)*K + k0 + cA, &lsB[chunk*512]);
    }
    __syncthreads();
    bf16x8 af[4], bfr[4];
    #pragma unroll
    for (int i=0;i<4;i++) af[i]  = *(const bf16x8*)&lsA[(wm*64 + i*16 + lo)*32 + (hi<<3)];
    #pragma unroll
    for (int j=0;j<4;j++) bfr[j] = *(const bf16x8*)&lsB[(wn*64 + j*16 + lo)*32 + (hi<<3)];
    #pragma unroll
    for (int i=0;i<4;i++)
      #pragma unroll
      for (int j=0;j<4;j++)
        acc[i][j] = __builtin_amdgcn_mfma_f32_16x16x32_bf16(af[i], bfr[j], acc[i][j], 0,0,0);
    __syncthreads();
  }

  float bv[4];
  #pragma unroll
  for (int j=0;j<4;j++) bv[j] = bias[n0 + wn*64 + j*16 + lo];
  #pragma unroll
  for (int i=0;i<4;i++){
    int row = m0 + wm*64 + i*16 + (hi<<2);
    #pragma unroll
    for (int j=0;j<4;j++){
      int col = n0 + wn*64 + j*16 + lo;
      #pragma unroll
      for (int r=0;r<4;r++){
        float vv = acc[i][j][r] + bv[j];
        if (F32OUT) ((float*)Cv)[(size_t)(row+r)*N + col] = vv;
        else        ((u16*)Cv)[(size_t)(row+r)*N + col] = f2bf(vv);
      }
    }
  }
}

// ---------------- causal flash attention (bf16 in/out, f32 softmax state) ----------------
// grid: (T/64, B*H); block 256 (4 independent waves, 16 q-rows each)
__global__ __launch_bounds__(256) void attn_fwd(const u16* __restrict__ qkv, const u16* __restrict__ vt,
                                                u16* __restrict__ y)
{
  __shared__ u16 plds[4][16*48];
  const int bh = blockIdx.y;
  const int b = bh >> 4, h = bh & 15;
  const int qt = blockIdx.x;
  const int w = threadIdx.x >> 6, lane = threadIdx.x & 63;
  const int qb = qt*64 + w*16;
  const int lo = lane & 15, hi = lane >> 4;

  const u16* Qb = qkv + (size_t)b*2048*6144 + h*128;       // s=0
  const u16* Kb = Qb + 2048;                               // s=1
  const u16* Vb = vt + (size_t)bh*128*2048;                // [d][t]

  bf16x8 qf[4];
  #pragma unroll
  for (int kd=0;kd<4;kd++)
    qf[kd] = *(const bf16x8*)&Qb[(size_t)(qb+lo)*6144 + kd*32 + hi*8];

  f32x4 o[8];
  f32x4 z = {0.f,0.f,0.f,0.f};
  #pragma unroll
  for (int dj=0;dj<8;dj++) o[dj] = z;
  float m2[4], ls[4];
  #pragma unroll
  for (int r=0;r<4;r++){ m2[r] = -3.0e38f; ls[r] = 0.f; }

  const float sc = 0.08838834764831845f * 1.4426950408889634f;  // 1/sqrt(128) * log2(e)
  const int kt_end = (qb + 15) >> 5;
  u16* pl = &plds[w][0];

  for (int kt = 0; kt <= kt_end; ++kt){
    f32x4 s0 = z, s1 = z;
    #pragma unroll
    for (int kd=0;kd<4;kd++){
      bf16x8 kf0 = *(const bf16x8*)&Kb[(size_t)(kt*32 + lo)*6144      + kd*32 + hi*8];
      bf16x8 kf1 = *(const bf16x8*)&Kb[(size_t)(kt*32 + 16 + lo)*6144 + kd*32 + hi*8];
      s0 = __builtin_amdgcn_mfma_f32_16x16x32_bf16(qf[kd], kf0, s0, 0,0,0);
      s1 = __builtin_amdgcn_mfma_f32_16x16x32_bf16(qf[kd], kf1, s1, 0,0,0);
    }
    #pragma unroll
    for (int r=0;r<4;r++){ s0[r] *= sc; s1[r] *= sc; }
    if (kt*32 + 31 > qb) {
      #pragma unroll
      for (int r=0;r<4;r++){
        int q = qb + hi*4 + r;
        if (kt*32 + lo > q)      s0[r] = -3.0e38f;
        if (kt*32 + 16 + lo > q) s1[r] = -3.0e38f;
      }
    }
    float p0[4], p1[4], al[4], rs[4];
    #pragma unroll
    for (int r=0;r<4;r++){
      float tm = fmaxf(s0[r], s1[r]);
      tm = fmaxf(tm, __shfl_xor(tm, 1));
      tm = fmaxf(tm, __shfl_xor(tm, 2));
      tm = fmaxf(tm, __shfl_xor(tm, 4));
      tm = fmaxf(tm, __shfl_xor(tm, 8));
      float mn = fmaxf(m2[r], tm);
      al[r] = exp2f(m2[r] - mn);
      m2[r] = mn;
      p0[r] = exp2f(s0[r] - mn);
      p1[r] = exp2f(s1[r] - mn);
      float sum = p0[r] + p1[r];
      sum += __shfl_xor(sum, 1);
      sum += __shfl_xor(sum, 2);
      sum += __shfl_xor(sum, 4);
      sum += __shfl_xor(sum, 8);
      rs[r] = sum;
    }
    #pragma unroll
    for (int r=0;r<4;r++) ls[r] = ls[r]*al[r] + rs[r];
    #pragma unroll
    for (int dj=0;dj<8;dj++)
      #pragma unroll
      for (int r=0;r<4;r++) o[dj][r] *= al[r];
    // P (16x32) -> per-wave LDS, then re-read as A-fragment
    #pragma unroll
    for (int r=0;r<4;r++){
      int rr = hi*4 + r;
      pl[rr*48 + lo]      = f2bf(p0[r]);
      pl[rr*48 + 16 + lo] = f2bf(p1[r]);
    }
    bf16x8 pf = *(const bf16x8*)&pl[lo*48 + hi*8];
    #pragma unroll
    for (int dj=0;dj<8;dj++){
      bf16x8 vf = *(const bf16x8*)&Vb[(size_t)(dj*16 + lo)*2048 + kt*32 + hi*8];
      o[dj] = __builtin_amdgcn_mfma_f32_16x16x32_bf16(pf, vf, o[dj], 0,0,0);
    }
  }
  #pragma unroll
  for (int r=0;r<4;r++) ls[r] = 1.0f / ls[r];
  #pragma unroll
  for (int dj=0;dj<8;dj++){
    #pragma unroll
    for (int r=0;r<4;r++){
      y[(size_t)(b*2048 + qb + hi*4 + r)*2048 + h*128 + dj*16 + lo] = f2bf(o[dj][r] * ls[r]);
    }
  }
}

extern "C" void kernel_launch(void* const* d_in, const int* in_sizes, int n_in,
                              void* d_out, int out_size, void* d_ws, size_t ws_size,
                              hipStream_t stream) {
  (void)in_sizes; (void)n_in; (void)out_size; (void)ws_size;
  const float* x      = (const float*)d_in[0];  // [8192][2048] f32
  const float* w_attn = (const float*)d_in[1];  // [2048][6144] f32
  const float* b_attn = (const float*)d_in[2];  // [6144] f32
  const float* w_proj = (const float*)d_in[3];  // [2048][2048] f32
  const float* b_proj = (const float*)d_in[4];  // [2048] f32
  float* out = (float*)d_out;                   // [8192][2048] f32

  char* ws = (char*)d_ws;
  u16* xbf = (u16*)(ws);                     // [8192][2048] bf16, 32 MB; reused as y after gemm1
  u16* wT  = (u16*)(ws + 33554432);          // [6144][2048] bf16, 24 MB
  u16* pT  = (u16*)(ws + 58720256);          // [2048][2048] bf16,  8 MB
  u16* qkv = (u16*)(ws + 67108864);          // [8192][6144] bf16, 96 MB
  u16* vt  = (u16*)(ws + 167772160);         // [64][128][2048] bf16, 32 MB
  u16* y   = xbf;                            // alias: x no longer needed after gemm1

  cvt_f2b<<<16384, 256, 0, stream>>>(x, xbf, 8192*2048);
  transpose2d_f2b<<<dim3(96,32), 256, 0, stream>>>(w_attn, wT, 2048, 6144);
  transpose2d_f2b<<<dim3(32,32), 256, 0, stream>>>(w_proj, pT, 2048, 2048);
  gemm_bt<0><<<dim3(48,64), 256, 0, stream>>>(xbf, wT, b_attn, qkv, 8192, 6144, 2048);
  transpose_v<<<dim3(2,32,64), 256, 0, stream>>>(qkv, vt);
  attn_fwd<<<dim3(32,64), 256, 0, stream>>>(qkv, vt, y);
  gemm_bt<1><<<dim3(16,64), 256, 0, stream>>>(y, pT, b_proj, out, 8192, 2048, 2048);
}

// Round 3
// 894.392 us; speedup vs baseline: 1.4495x; 1.4495x over previous
//
#include <hip/hip_runtime.h>
#include <hip/hip_bf16.h>
#include <stdint.h>

typedef unsigned short u16;
typedef __bf16 bf16x8 __attribute__((ext_vector_type(8)));
typedef unsigned short u16x8 __attribute__((ext_vector_type(8)));
typedef float f32x4 __attribute__((ext_vector_type(4)));

__device__ __forceinline__ float bf2f(u16 u){ union{float f; unsigned i;} v; v.i = ((unsigned)u)<<16; return v.f; }
__device__ __forceinline__ u16 f2bf(float f){ union{float f; unsigned i;} v; v.f=f; unsigned r = v.i + 0x7FFFu + ((v.i>>16)&1u); return (u16)(r>>16); }

__device__ __forceinline__ void async16(const void* g, void* l){
  __builtin_amdgcn_global_load_lds((const __attribute__((address_space(1))) void*)g,
                                   (__attribute__((address_space(3))) void*)l, 16, 0, 0);
}

// ---------------- f32 -> bf16 elementwise cast (vectorized) ----------------
__global__ __launch_bounds__(256) void cvt_f2b(const float* __restrict__ src, u16* __restrict__ dst, int n)
{
  int i = (blockIdx.x * 256 + threadIdx.x) * 4;
  if (i < n) {
    float4 v = *(const float4*)&src[i];
    ushort4 o;
    o.x = f2bf(v.x); o.y = f2bf(v.y); o.z = f2bf(v.z); o.w = f2bf(v.w);
    *(ushort4*)&dst[i] = o;
  }
}

// ---------------- f32 src -> bf16 transposed dst, 64x64 tiles ----------------
__global__ __launch_bounds__(256) void transpose2d_f2b(const float* __restrict__ src, u16* __restrict__ dst,
                                                       int src_rows, int src_cols)
{
  __shared__ u16 tile[64][72];
  const int r0 = blockIdx.y << 6, c0 = blockIdx.x << 6;
  const int t = threadIdx.x;
  #pragma unroll
  for (int i=0;i<4;i++){
    int slot = t + (i<<8);
    int r = slot >> 4, cv = (slot & 15) << 2;
    float4 v = *(const float4*)&src[(size_t)(r0+r)*src_cols + c0 + cv];
    tile[r][cv+0] = f2bf(v.x); tile[r][cv+1] = f2bf(v.y);
    tile[r][cv+2] = f2bf(v.z); tile[r][cv+3] = f2bf(v.w);
  }
  __syncthreads();
  #pragma unroll
  for (int i=0;i<2;i++){
    int slot = t + (i<<8);
    int cr = slot >> 3, rv = (slot & 7) << 3;
    u16x8 v;
    #pragma unroll
    for (int e=0;e<8;e++) v[e] = tile[rv+e][cr];
    *(u16x8*)&dst[(size_t)(c0+cr)*src_rows + r0 + rv] = v;
  }
}

// ---------------- V transpose: qkv[b,t, 2*2048 + h*128 + d] -> vt[bh][d][t] (bf16) ----------------
__global__ __launch_bounds__(256) void transpose_v(const u16* __restrict__ qkv, u16* __restrict__ vt)
{
  __shared__ u16 tile[64][72];
  const int bh = blockIdx.z;
  const int b = bh >> 4, h = bh & 15;
  const u16* src = qkv + (size_t)b*2048*6144 + 4096 + h*128;
  u16* dst = vt + (size_t)bh*128*2048;
  const int t0 = blockIdx.y << 6, d0 = blockIdx.x << 6;
  const int t = threadIdx.x;
  #pragma unroll
  for (int i=0;i<2;i++){
    int slot = t + (i<<8);
    int r = slot >> 3, cv = (slot & 7) << 3;
    *(u16x8*)&tile[r][cv] = *(const u16x8*)&src[(size_t)(t0+r)*6144 + d0 + cv];
  }
  __syncthreads();
  #pragma unroll
  for (int i=0;i<2;i++){
    int slot = t + (i<<8);
    int cr = slot >> 3, rv = (slot & 7) << 3;
    u16x8 v;
    #pragma unroll
    for (int e=0;e<8;e++) v[e] = tile[rv+e][cr];
    *(u16x8*)&dst[(size_t)(d0+cr)*2048 + t0 + rv] = v;
  }
}

// ---------------- GEMM C = A * Bt^T + bias (bf16 in, f32 accum) ----------------
template<int F32OUT>
__global__ __launch_bounds__(256) void gemm_bt(const u16* __restrict__ A, const u16* __restrict__ Bt,
                                               const float* __restrict__ bias, void* __restrict__ Cv,
                                               int M, int N, int K)
{
  __shared__ u16 lsA[128*32];
  __shared__ u16 lsB[128*32];
  const int tid = threadIdx.x;
  const int w = tid >> 6, lane = tid & 63;
  const int wm = w >> 1, wn = w & 1;
  const int m0 = blockIdx.y << 7, n0 = blockIdx.x << 7;
  const int lo = lane & 15, hi = lane >> 4;

  f32x4 acc[4][4];
  f32x4 z = {0.f,0.f,0.f,0.f};
  #pragma unroll
  for (int i=0;i<4;i++)
    #pragma unroll
    for (int j=0;j<4;j++) acc[i][j] = z;

  const int rA = lane >> 2;
  const int cA = (lane & 3) << 3;

  for (int k0 = 0; k0 < K; k0 += 32) {
    #pragma unroll
    for (int i=0;i<2;i++){
      int chunk = w + (i<<2);
      async16(A  + (size_t)(m0 + chunk*16 + rA)*K + k0 + cA, &lsA[chunk*512]);
      async16(Bt + (size_t)(n0 + chunk*16 + rA)*K + k0 + cA, &lsB[chunk*512]);
    }
    __syncthreads();
    bf16x8 af[4], bfr[4];
    #pragma unroll
    for (int i=0;i<4;i++) af[i]  = *(const bf16x8*)&lsA[(wm*64 + i*16 + lo)*32 + (hi<<3)];
    #pragma unroll
    for (int j=0;j<4;j++) bfr[j] = *(const bf16x8*)&lsB[(wn*64 + j*16 + lo)*32 + (hi<<3)];
    #pragma unroll
    for (int i=0;i<4;i++)
      #pragma unroll
      for (int j=0;j<4;j++)
        acc[i][j] = __builtin_amdgcn_mfma_f32_16x16x32_bf16(af[i], bfr[j], acc[i][j], 0,0,0);
    __syncthreads();
  }

  float bv[4];
  #pragma unroll
  for (int j=0;j<4;j++) bv[j] = bias[n0 + wn*64 + j*16 + lo];
  #pragma unroll
  for (int i=0;i<4;i++){
    int row = m0 + wm*64 + i*16 + (hi<<2);
    #pragma unroll
    for (int j=0;j<4;j++){
      int col = n0 + wn*64 + j*16 + lo;
      #pragma unroll
      for (int r=0;r<4;r++){
        float vv = acc[i][j][r] + bv[j];
        if (F32OUT) ((float*)Cv)[(size_t)(row+r)*N + col] = vv;
        else        ((u16*)Cv)[(size_t)(row+r)*N + col] = f2bf(vv);
      }
    }
  }
}

// ---------------- causal flash attention v2 ----------------
// grid: (16, B*H) with qt = 15-blockIdx.x; block 256 = 4 waves.
// Block handles 128 q-rows (wave: 32). K/V tiles of 64 staged in LDS (swizzled),
// shared by all waves. P via per-wave padded LDS buffer.
__global__ __launch_bounds__(256) void attn_fwd(const u16* __restrict__ qkv, const u16* __restrict__ vt,
                                                u16* __restrict__ y)
{
  __shared__ u16 kbuf[64*128];     // [krow][d]  (cols XOR-swizzled by (krow&7)<<4 bytes)
  __shared__ u16 vbuf[128*64];     // [d][kcol]  (cols XOR-swizzled by (drow&7)<<4 bytes)
  __shared__ u16 plds[4][32*72];   // per-wave P tile [32 q][64 k], pad to 72
  const int bh = blockIdx.y;
  const int b = bh >> 4, h = bh & 15;
  const int qt = 15 - blockIdx.x;            // longest blocks first
  const int tid = threadIdx.x;
  const int w = tid >> 6, lane = tid & 63;
  const int lo = lane & 15, hi = lane >> 4;
  const int qw = qt*128 + w*32;              // wave's first q-row

  const u16* Qb = qkv + (size_t)b*2048*6144 + h*128;  // Q
  const u16* Kb = Qb + 2048;                          // K
  const u16* Vb = vt + (size_t)bh*128*2048;           // V^T [d][t]

  bf16x8 qf[2][4];
  #pragma unroll
  for (int f=0;f<2;f++)
    #pragma unroll
    for (int kd=0;kd<4;kd++)
      qf[f][kd] = *(const bf16x8*)&Qb[(size_t)(qw + f*16 + lo)*6144 + kd*32 + hi*8];

  f32x4 o[2][8];
  f32x4 z = {0.f,0.f,0.f,0.f};
  #pragma unroll
  for (int f=0;f<2;f++)
    #pragma unroll
    for (int dj=0;dj<8;dj++) o[f][dj] = z;
  float mx[2][4], lsum[2][4];
  #pragma unroll
  for (int f=0;f<2;f++)
    #pragma unroll
    for (int r=0;r<4;r++){ mx[f][r] = -3.0e38f; lsum[f][r] = 0.f; }

  const float sc = 0.08838834764831845f * 1.4426950408889634f;  // 1/sqrt(128)*log2(e)
  const int nt = qt*2 + 2;
  u16* pw = &plds[w][0];

  for (int it = 0; it < nt; ++it){
    const int k0 = it*64;
    __syncthreads();   // everyone done reading previous K/V tile
    #pragma unroll
    for (int i=0;i<4;i++){
      int slot = i*256 + tid;
      int kr = slot >> 4;
      int kc = ((slot & 15) << 4) ^ ((kr & 7) << 4);   // swizzled source byte-col
      async16(Kb + (size_t)(k0 + kr)*6144 + (kc >> 1), &kbuf[(size_t)(i*256 + w*64)*8]);
      int vr = slot >> 3;
      int vc = ((slot & 7) << 4) ^ ((vr & 7) << 4);
      async16(Vb + (size_t)vr*2048 + k0 + (vc >> 1), &vbuf[(size_t)(i*256 + w*64)*8]);
    }
    __syncthreads();   // staged data visible (vmcnt drained by barrier)
    if (k0 > qw + 31) continue;   // wave fully masked; barriers already passed

    // ---- QK^T: S[32q x 64k] ----
    f32x4 s[2][4];
    #pragma unroll
    for (int f=0;f<2;f++)
      #pragma unroll
      for (int t=0;t<4;t++) s[f][t] = z;
    #pragma unroll
    for (int t=0;t<4;t++){
      bf16x8 kk[4];
      #pragma unroll
      for (int kd=0;kd<4;kd++){
        int row = t*16 + lo;
        int cb = (kd*64 + hi*16) ^ ((lo & 7) << 4);
        kk[kd] = *(const bf16x8*)&kbuf[row*128 + (cb >> 1)];
      }
      #pragma unroll
      for (int f=0;f<2;f++)
        #pragma unroll
        for (int kd=0;kd<4;kd++)
          s[f][t] = __builtin_amdgcn_mfma_f32_16x16x32_bf16(qf[f][kd], kk[kd], s[f][t], 0,0,0);
    }

    // ---- scale + causal mask + online softmax ----
    #pragma unroll
    for (int f=0;f<2;f++){
      #pragma unroll
      for (int t=0;t<4;t++)
        #pragma unroll
        for (int r=0;r<4;r++) s[f][t][r] *= sc;
      if (k0 + 63 > qw + f*16) {
        #pragma unroll
        for (int t=0;t<4;t++)
          #pragma unroll
          for (int r=0;r<4;r++){
            int q = qw + f*16 + hi*4 + r;
            int k = k0 + t*16 + lo;
            if (k > q) s[f][t][r] = -3.0e38f;
          }
      }
      #pragma unroll
      for (int r=0;r<4;r++){
        float tm = fmaxf(fmaxf(s[f][0][r], s[f][1][r]), fmaxf(s[f][2][r], s[f][3][r]));
        tm = fmaxf(tm, __shfl_xor(tm, 1));
        tm = fmaxf(tm, __shfl_xor(tm, 2));
        tm = fmaxf(tm, __shfl_xor(tm, 4));
        tm = fmaxf(tm, __shfl_xor(tm, 8));
        float mn = fmaxf(mx[f][r], tm);
        float al = exp2f(mx[f][r] - mn);
        mx[f][r] = mn;
        float p0 = exp2f(s[f][0][r] - mn);
        float p1 = exp2f(s[f][1][r] - mn);
        float p2 = exp2f(s[f][2][r] - mn);
        float p3 = exp2f(s[f][3][r] - mn);
        float sum = (p0 + p1) + (p2 + p3);
        sum += __shfl_xor(sum, 1);
        sum += __shfl_xor(sum, 2);
        sum += __shfl_xor(sum, 4);
        sum += __shfl_xor(sum, 8);
        lsum[f][r] = lsum[f][r]*al + sum;
        #pragma unroll
        for (int dj=0;dj<8;dj++) o[f][dj][r] *= al;
        u16* pr = &pw[(f*16 + hi*4 + r)*72];
        pr[lo]      = f2bf(p0);
        pr[16 + lo] = f2bf(p1);
        pr[32 + lo] = f2bf(p2);
        pr[48 + lo] = f2bf(p3);
      }
    }

    // ---- PV: O += P[32x64] * V[64x128] ----
    bf16x8 pa[2][2];
    #pragma unroll
    for (int f=0;f<2;f++)
      #pragma unroll
      for (int kf=0;kf<2;kf++)
        pa[f][kf] = *(const bf16x8*)&pw[(f*16 + lo)*72 + kf*32 + hi*8];
    #pragma unroll
    for (int dj=0;dj<8;dj++){
      int row = dj*16 + lo;
      int cb0 = (hi*16)      ^ ((lo & 7) << 4);
      int cb1 = (64 + hi*16) ^ ((lo & 7) << 4);
      bf16x8 vv0 = *(const bf16x8*)&vbuf[row*64 + (cb0 >> 1)];
      bf16x8 vv1 = *(const bf16x8*)&vbuf[row*64 + (cb1 >> 1)];
      #pragma unroll
      for (int f=0;f<2;f++){
        o[f][dj] = __builtin_amdgcn_mfma_f32_16x16x32_bf16(pa[f][0], vv0, o[f][dj], 0,0,0);
        o[f][dj] = __builtin_amdgcn_mfma_f32_16x16x32_bf16(pa[f][1], vv1, o[f][dj], 0,0,0);
      }
    }
  }

  // ---- epilogue ----
  #pragma unroll
  for (int f=0;f<2;f++)
    #pragma unroll
    for (int r=0;r<4;r++){
      float inv = 1.0f / lsum[f][r];
      int row = b*2048 + qw + f*16 + hi*4 + r;
      #pragma unroll
      for (int dj=0;dj<8;dj++)
        y[(size_t)row*2048 + h*128 + dj*16 + lo] = f2bf(o[f][dj][r] * inv);
    }
}

extern "C" void kernel_launch(void* const* d_in, const int* in_sizes, int n_in,
                              void* d_out, int out_size, void* d_ws, size_t ws_size,
                              hipStream_t stream) {
  (void)in_sizes; (void)n_in; (void)out_size; (void)ws_size;
  const float* x      = (const float*)d_in[0];  // [8192][2048] f32
  const float* w_attn = (const float*)d_in[1];  // [2048][6144] f32
  const float* b_attn = (const float*)d_in[2];  // [6144] f32
  const float* w_proj = (const float*)d_in[3];  // [2048][2048] f32
  const float* b_proj = (const float*)d_in[4];  // [2048] f32
  float* out = (float*)d_out;                   // [8192][2048] f32

  char* ws = (char*)d_ws;
  u16* xbf = (u16*)(ws);                     // [8192][2048] bf16, 32 MB; reused as y
  u16* wT  = (u16*)(ws + 33554432);          // [6144][2048] bf16, 24 MB
  u16* pT  = (u16*)(ws + 58720256);          // [2048][2048] bf16,  8 MB
  u16* qkv = (u16*)(ws + 67108864);          // [8192][6144] bf16, 96 MB
  u16* vt  = (u16*)(ws + 167772160);         // [64][128][2048] bf16, 32 MB
  u16* y   = xbf;

  cvt_f2b<<<16384, 256, 0, stream>>>(x, xbf, 8192*2048);
  transpose2d_f2b<<<dim3(96,32), 256, 0, stream>>>(w_attn, wT, 2048, 6144);
  transpose2d_f2b<<<dim3(32,32), 256, 0, stream>>>(w_proj, pT, 2048, 2048);
  gemm_bt<0><<<dim3(48,64), 256, 0, stream>>>(xbf, wT, b_attn, qkv, 8192, 6144, 2048);
  transpose_v<<<dim3(2,32,64), 256, 0, stream>>>(qkv, vt);
  attn_fwd<<<dim3(16,64), 256, 0, stream>>>(qkv, vt, y);
  gemm_bt<1><<<dim3(16,64), 256, 0, stream>>>(y, pT, b_proj, out, 8192, 2048, 2048);
}

// Round 4
// 794.214 us; speedup vs baseline: 1.6323x; 1.1261x over previous
//
#include <hip/hip_runtime.h>
#include <hip/hip_bf16.h>
#include <stdint.h>

typedef unsigned short u16;
typedef __bf16 bf16x8 __attribute__((ext_vector_type(8)));
typedef unsigned short u16x8 __attribute__((ext_vector_type(8)));
typedef float f32x4 __attribute__((ext_vector_type(4)));

__device__ __forceinline__ float bf2f(u16 u){ union{float f; unsigned i;} v; v.i = ((unsigned)u)<<16; return v.f; }
__device__ __forceinline__ u16 f2bf(float f){ union{float f; unsigned i;} v; v.f=f; unsigned r = v.i + 0x7FFFu + ((v.i>>16)&1u); return (u16)(r>>16); }

__device__ __forceinline__ void async16(const void* g, void* l){
  __builtin_amdgcn_global_load_lds((const __attribute__((address_space(1))) void*)g,
                                   (__attribute__((address_space(3))) void*)l, 16, 0, 0);
}

// ---------------- f32 -> bf16 elementwise cast (vectorized) ----------------
__global__ __launch_bounds__(256) void cvt_f2b(const float* __restrict__ src, u16* __restrict__ dst, int n)
{
  int i = (blockIdx.x * 256 + threadIdx.x) * 4;
  if (i < n) {
    float4 v = *(const float4*)&src[i];
    ushort4 o;
    o.x = f2bf(v.x); o.y = f2bf(v.y); o.z = f2bf(v.z); o.w = f2bf(v.w);
    *(ushort4*)&dst[i] = o;
  }
}

// ---------------- f32 src -> bf16 transposed dst, 64x64 tiles ----------------
__global__ __launch_bounds__(256) void transpose2d_f2b(const float* __restrict__ src, u16* __restrict__ dst,
                                                       int src_rows, int src_cols)
{
  __shared__ u16 tile[64][72];
  const int r0 = blockIdx.y << 6, c0 = blockIdx.x << 6;
  const int t = threadIdx.x;
  #pragma unroll
  for (int i=0;i<4;i++){
    int slot = t + (i<<8);
    int r = slot >> 4, cv = (slot & 15) << 2;
    float4 v = *(const float4*)&src[(size_t)(r0+r)*src_cols + c0 + cv];
    tile[r][cv+0] = f2bf(v.x); tile[r][cv+1] = f2bf(v.y);
    tile[r][cv+2] = f2bf(v.z); tile[r][cv+3] = f2bf(v.w);
  }
  __syncthreads();
  #pragma unroll
  for (int i=0;i<2;i++){
    int slot = t + (i<<8);
    int cr = slot >> 3, rv = (slot & 7) << 3;
    u16x8 v;
    #pragma unroll
    for (int e=0;e<8;e++) v[e] = tile[rv+e][cr];
    *(u16x8*)&dst[(size_t)(c0+cr)*src_rows + r0 + rv] = v;
  }
}

// ---------------- V transpose: qkv[b,t, 2*2048 + h*128 + d] -> vt[bh][d][t] (bf16) ----------------
__global__ __launch_bounds__(256) void transpose_v(const u16* __restrict__ qkv, u16* __restrict__ vt)
{
  __shared__ u16 tile[64][72];
  const int bh = blockIdx.z;
  const int b = bh >> 4, h = bh & 15;
  const u16* src = qkv + (size_t)b*2048*6144 + 4096 + h*128;
  u16* dst = vt + (size_t)bh*128*2048;
  const int t0 = blockIdx.y << 6, d0 = blockIdx.x << 6;
  const int t = threadIdx.x;
  #pragma unroll
  for (int i=0;i<2;i++){
    int slot = t + (i<<8);
    int r = slot >> 3, cv = (slot & 7) << 3;
    *(u16x8*)&tile[r][cv] = *(const u16x8*)&src[(size_t)(t0+r)*6144 + d0 + cv];
  }
  __syncthreads();
  #pragma unroll
  for (int i=0;i<2;i++){
    int slot = t + (i<<8);
    int cr = slot >> 3, rv = (slot & 7) << 3;
    u16x8 v;
    #pragma unroll
    for (int e=0;e<8;e++) v[e] = tile[rv+e][cr];
    *(u16x8*)&dst[(size_t)(d0+cr)*2048 + t0 + rv] = v;
  }
}

// ---------------- GEMM C = A * Bt^T + bias (bf16 in, f32 accum) ----------------
template<int F32OUT>
__global__ __launch_bounds__(256) void gemm_bt(const u16* __restrict__ A, const u16* __restrict__ Bt,
                                               const float* __restrict__ bias, void* __restrict__ Cv,
                                               int M, int N, int K)
{
  __shared__ u16 lsA[128*32];
  __shared__ u16 lsB[128*32];
  const int tid = threadIdx.x;
  const int w = tid >> 6, lane = tid & 63;
  const int wm = w >> 1, wn = w & 1;
  const int m0 = blockIdx.y << 7, n0 = blockIdx.x << 7;
  const int lo = lane & 15, hi = lane >> 4;

  f32x4 acc[4][4];
  f32x4 z = {0.f,0.f,0.f,0.f};
  #pragma unroll
  for (int i=0;i<4;i++)
    #pragma unroll
    for (int j=0;j<4;j++) acc[i][j] = z;

  const int rA = lane >> 2;
  const int cA = (lane & 3) << 3;

  for (int k0 = 0; k0 < K; k0 += 32) {
    #pragma unroll
    for (int i=0;i<2;i++){
      int chunk = w + (i<<2);
      async16(A  + (size_t)(m0 + chunk*16 + rA)*K + k0 + cA, &lsA[chunk*512]);
      async16(Bt + (size_t)(n0 + chunk*16 + rA)*K + k0 + cA, &lsB[chunk*512]);
    }
    __syncthreads();
    bf16x8 af[4], bfr[4];
    #pragma unroll
    for (int i=0;i<4;i++) af[i]  = *(const bf16x8*)&lsA[(wm*64 + i*16 + lo)*32 + (hi<<3)];
    #pragma unroll
    for (int j=0;j<4;j++) bfr[j] = *(const bf16x8*)&lsB[(wn*64 + j*16 + lo)*32 + (hi<<3)];
    #pragma unroll
    for (int i=0;i<4;i++)
      #pragma unroll
      for (int j=0;j<4;j++)
        acc[i][j] = __builtin_amdgcn_mfma_f32_16x16x32_bf16(af[i], bfr[j], acc[i][j], 0,0,0);
    __syncthreads();
  }

  float bv[4];
  #pragma unroll
  for (int j=0;j<4;j++) bv[j] = bias[n0 + wn*64 + j*16 + lo];
  #pragma unroll
  for (int i=0;i<4;i++){
    int row = m0 + wm*64 + i*16 + (hi<<2);
    #pragma unroll
    for (int j=0;j<4;j++){
      int col = n0 + wn*64 + j*16 + lo;
      #pragma unroll
      for (int r=0;r<4;r++){
        float vv = acc[i][j][r] + bv[j];
        if (F32OUT) ((float*)Cv)[(size_t)(row+r)*N + col] = vv;
        else        ((u16*)Cv)[(size_t)(row+r)*N + col] = f2bf(vv);
      }
    }
  }
}

// ---------------- causal flash attention v3 ----------------
// grid: (8, B*H); block 256 = 4 waves. Triangle pairing: block handles q-tiles
// (15-pair) then (pair) -> 34 K-tiles per block, uniform. K double-buffered in
// LDS (XOR-swizzled); V read direct from global V^T (L2-resident).
__global__ __launch_bounds__(256) void attn_fwd(const u16* __restrict__ qkv, const u16* __restrict__ vt,
                                                u16* __restrict__ y)
{
  __shared__ u16 kb[2][64*128];    // K tile dbuf [krow][d], cols XOR-swizzled by (krow&7)<<4 bytes
  __shared__ u16 plds[4][32*72];   // per-wave P tile [32 q][64 k], pad 72
  const int bh = blockIdx.y;
  const int b = bh >> 4, h = bh & 15;
  const int pair = blockIdx.x;     // 0..7
  const int tid = threadIdx.x;
  const int w = tid >> 6, lane = tid & 63;
  const int lo = lane & 15, hi = lane >> 4;

  const u16* Qb = qkv + (size_t)b*2048*6144 + h*128;
  const u16* Kb = Qb + 2048;
  const u16* Vb = vt + (size_t)bh*128*2048;   // [d][t]
  u16* pw = &plds[w][0];
  const float sc = 0.08838834764831845f * 1.4426950408889634f;  // 1/sqrt(128)*log2(e)
  f32x4 z = {0.f,0.f,0.f,0.f};

  #pragma unroll 1
  for (int seg = 0; seg < 2; ++seg){
    const int qt = seg ? pair : 15 - pair;
    const int qw = qt*128 + w*32;
    const int nt = qt*2 + 2;

    bf16x8 qf[2][4];
    #pragma unroll
    for (int f=0;f<2;f++)
      #pragma unroll
      for (int kd=0;kd<4;kd++)
        qf[f][kd] = *(const bf16x8*)&Qb[(size_t)(qw + f*16 + lo)*6144 + kd*32 + hi*8];

    f32x4 o[2][8];
    #pragma unroll
    for (int f=0;f<2;f++)
      #pragma unroll
      for (int dj=0;dj<8;dj++) o[f][dj] = z;
    float mx[2][4], lsum[2][4];
    #pragma unroll
    for (int f=0;f<2;f++)
      #pragma unroll
      for (int r=0;r<4;r++){ mx[f][r] = -3.0e38f; lsum[f][r] = 0.f; }

    // prologue: stage tile 0 into kb[0]
    #pragma unroll
    for (int i=0;i<4;i++){
      int slot = i*256 + tid;
      int kr = slot >> 4;
      int kc = ((slot & 15) << 4) ^ ((kr & 7) << 4);
      async16(Kb + (size_t)kr*6144 + (kc >> 1), &kb[0][(size_t)(i*256 + w*64)*8]);
    }
    __syncthreads();

    #pragma unroll 1
    for (int it = 0; it < nt; ++it){
      const int k0 = it*64;
      // issue next tile's stage into the other buffer (overlaps with compute)
      if (it + 1 < nt){
        const int kn = (it+1)*64;
        u16* dst = kb[(it+1)&1];
        #pragma unroll
        for (int i=0;i<4;i++){
          int slot = i*256 + tid;
          int kr = slot >> 4;
          int kc = ((slot & 15) << 4) ^ ((kr & 7) << 4);
          async16(Kb + (size_t)(kn + kr)*6144 + (kc >> 1), &dst[(size_t)(i*256 + w*64)*8]);
        }
      }
      if (k0 <= qw + 31){
        const u16* kcur = kb[it&1];
        // ---- QK^T: S[32q x 64k] ----
        f32x4 s[2][4];
        #pragma unroll
        for (int f=0;f<2;f++)
          #pragma unroll
          for (int t=0;t<4;t++) s[f][t] = z;
        __builtin_amdgcn_s_setprio(1);
        #pragma unroll
        for (int t=0;t<4;t++){
          bf16x8 kk[4];
          #pragma unroll
          for (int kd=0;kd<4;kd++){
            int row = t*16 + lo;
            int cb = (kd*64 + hi*16) ^ ((lo & 7) << 4);
            kk[kd] = *(const bf16x8*)&kcur[row*128 + (cb >> 1)];
          }
          #pragma unroll
          for (int f=0;f<2;f++)
            #pragma unroll
            for (int kd=0;kd<4;kd++)
              s[f][t] = __builtin_amdgcn_mfma_f32_16x16x32_bf16(qf[f][kd], kk[kd], s[f][t], 0,0,0);
        }
        __builtin_amdgcn_s_setprio(0);

        // ---- scale + causal mask + online softmax ----
        #pragma unroll
        for (int f=0;f<2;f++){
          #pragma unroll
          for (int t=0;t<4;t++)
            #pragma unroll
            for (int r=0;r<4;r++) s[f][t][r] *= sc;
          if (k0 + 63 > qw + f*16) {
            #pragma unroll
            for (int t=0;t<4;t++)
              #pragma unroll
              for (int r=0;r<4;r++){
                int q = qw + f*16 + hi*4 + r;
                int k = k0 + t*16 + lo;
                if (k > q) s[f][t][r] = -3.0e38f;
              }
          }
          #pragma unroll
          for (int r=0;r<4;r++){
            float tm = fmaxf(fmaxf(s[f][0][r], s[f][1][r]), fmaxf(s[f][2][r], s[f][3][r]));
            tm = fmaxf(tm, __shfl_xor(tm, 1));
            tm = fmaxf(tm, __shfl_xor(tm, 2));
            tm = fmaxf(tm, __shfl_xor(tm, 4));
            tm = fmaxf(tm, __shfl_xor(tm, 8));
            float mn = fmaxf(mx[f][r], tm);
            float al = exp2f(mx[f][r] - mn);
            mx[f][r] = mn;
            float p0 = exp2f(s[f][0][r] - mn);
            float p1 = exp2f(s[f][1][r] - mn);
            float p2 = exp2f(s[f][2][r] - mn);
            float p3 = exp2f(s[f][3][r] - mn);
            float sum = (p0 + p1) + (p2 + p3);
            sum += __shfl_xor(sum, 1);
            sum += __shfl_xor(sum, 2);
            sum += __shfl_xor(sum, 4);
            sum += __shfl_xor(sum, 8);
            lsum[f][r] = lsum[f][r]*al + sum;
            #pragma unroll
            for (int dj=0;dj<8;dj++) o[f][dj][r] *= al;
            u16* pr = &pw[(f*16 + hi*4 + r)*72];
            pr[lo]      = f2bf(p0);
            pr[16 + lo] = f2bf(p1);
            pr[32 + lo] = f2bf(p2);
            pr[48 + lo] = f2bf(p3);
          }
        }

        // ---- PV: O += P[32x64] * V[64x128], V direct from global V^T ----
        bf16x8 pa[2][2];
        #pragma unroll
        for (int f=0;f<2;f++)
          #pragma unroll
          for (int kf=0;kf<2;kf++)
            pa[f][kf] = *(const bf16x8*)&pw[(f*16 + lo)*72 + kf*32 + hi*8];
        __builtin_amdgcn_s_setprio(1);
        #pragma unroll
        for (int dj=0;dj<8;dj++){
          const u16* vr = &Vb[(size_t)(dj*16 + lo)*2048 + k0];
          bf16x8 vv0 = *(const bf16x8*)&vr[hi*8];
          bf16x8 vv1 = *(const bf16x8*)&vr[32 + hi*8];
          #pragma unroll
          for (int f=0;f<2;f++){
            o[f][dj] = __builtin_amdgcn_mfma_f32_16x16x32_bf16(pa[f][0], vv0, o[f][dj], 0,0,0);
            o[f][dj] = __builtin_amdgcn_mfma_f32_16x16x32_bf16(pa[f][1], vv1, o[f][dj], 0,0,0);
          }
        }
        __builtin_amdgcn_s_setprio(0);
      }
      __syncthreads();   // drains stage loads (vmcnt) + releases kb[it&1] for overwrite
    }

    // ---- epilogue ----
    #pragma unroll
    for (int f=0;f<2;f++)
      #pragma unroll
      for (int r=0;r<4;r++){
        float inv = 1.0f / lsum[f][r];
        int row = b*2048 + qw + f*16 + hi*4 + r;
        #pragma unroll
        for (int dj=0;dj<8;dj++)
          y[(size_t)row*2048 + h*128 + dj*16 + lo] = f2bf(o[f][dj][r] * inv);
      }
    __syncthreads();   // keep segments separated (kb reuse)
  }
}

extern "C" void kernel_launch(void* const* d_in, const int* in_sizes, int n_in,
                              void* d_out, int out_size, void* d_ws, size_t ws_size,
                              hipStream_t stream) {
  (void)in_sizes; (void)n_in; (void)out_size; (void)ws_size;
  const float* x      = (const float*)d_in[0];  // [8192][2048] f32
  const float* w_attn = (const float*)d_in[1];  // [2048][6144] f32
  const float* b_attn = (const float*)d_in[2];  // [6144] f32
  const float* w_proj = (const float*)d_in[3];  // [2048][2048] f32
  const float* b_proj = (const float*)d_in[4];  // [2048] f32
  float* out = (float*)d_out;                   // [8192][2048] f32

  char* ws = (char*)d_ws;
  u16* xbf = (u16*)(ws);                     // [8192][2048] bf16, 32 MB; reused as y
  u16* wT  = (u16*)(ws + 33554432);          // [6144][2048] bf16, 24 MB
  u16* pT  = (u16*)(ws + 58720256);          // [2048][2048] bf16,  8 MB
  u16* qkv = (u16*)(ws + 67108864);          // [8192][6144] bf16, 96 MB
  u16* vt  = (u16*)(ws + 167772160);         // [64][128][2048] bf16, 32 MB
  u16* y   = xbf;

  cvt_f2b<<<16384, 256, 0, stream>>>(x, xbf, 8192*2048);
  transpose2d_f2b<<<dim3(96,32), 256, 0, stream>>>(w_attn, wT, 2048, 6144);
  transpose2d_f2b<<<dim3(32,32), 256, 0, stream>>>(w_proj, pT, 2048, 2048);
  gemm_bt<0><<<dim3(48,64), 256, 0, stream>>>(xbf, wT, b_attn, qkv, 8192, 6144, 2048);
  transpose_v<<<dim3(2,32,64), 256, 0, stream>>>(qkv, vt);
  attn_fwd<<<dim3(8,64), 256, 0, stream>>>(qkv, vt, y);
  gemm_bt<1><<<dim3(16,64), 256, 0, stream>>>(y, pT, b_proj, out, 8192, 2048, 2048);
}

// Round 5
// 733.043 us; speedup vs baseline: 1.7685x; 1.0834x over previous
//
#include <hip/hip_runtime.h>
#include <hip/hip_bf16.h>
#include <stdint.h>

typedef unsigned short u16;
typedef __bf16 bf16x8 __attribute__((ext_vector_type(8)));
typedef unsigned short u16x8 __attribute__((ext_vector_type(8)));
typedef float f32x4 __attribute__((ext_vector_type(4)));

__device__ __forceinline__ float bf2f(u16 u){ union{float f; unsigned i;} v; v.i = ((unsigned)u)<<16; return v.f; }
__device__ __forceinline__ u16 f2bf(float f){ union{float f; unsigned i;} v; v.f=f; unsigned r = v.i + 0x7FFFu + ((v.i>>16)&1u); return (u16)(r>>16); }

__device__ __forceinline__ void async16(const void* g, void* l){
  __builtin_amdgcn_global_load_lds((const __attribute__((address_space(1))) void*)g,
                                   (__attribute__((address_space(3))) void*)l, 16, 0, 0);
}

// ---------------- f32 -> bf16 elementwise cast (vectorized) ----------------
__global__ __launch_bounds__(256) void cvt_f2b(const float* __restrict__ src, u16* __restrict__ dst, int n)
{
  int i = (blockIdx.x * 256 + threadIdx.x) * 4;
  if (i < n) {
    float4 v = *(const float4*)&src[i];
    ushort4 o;
    o.x = f2bf(v.x); o.y = f2bf(v.y); o.z = f2bf(v.z); o.w = f2bf(v.w);
    *(ushort4*)&dst[i] = o;
  }
}

// ---------------- f32 src -> bf16 transposed dst, 64x64 tiles ----------------
__global__ __launch_bounds__(256) void transpose2d_f2b(const float* __restrict__ src, u16* __restrict__ dst,
                                                       int src_rows, int src_cols)
{
  __shared__ u16 tile[64][72];
  const int r0 = blockIdx.y << 6, c0 = blockIdx.x << 6;
  const int t = threadIdx.x;
  #pragma unroll
  for (int i=0;i<4;i++){
    int slot = t + (i<<8);
    int r = slot >> 4, cv = (slot & 15) << 2;
    float4 v = *(const float4*)&src[(size_t)(r0+r)*src_cols + c0 + cv];
    tile[r][cv+0] = f2bf(v.x); tile[r][cv+1] = f2bf(v.y);
    tile[r][cv+2] = f2bf(v.z); tile[r][cv+3] = f2bf(v.w);
  }
  __syncthreads();
  #pragma unroll
  for (int i=0;i<2;i++){
    int slot = t + (i<<8);
    int cr = slot >> 3, rv = (slot & 7) << 3;
    u16x8 v;
    #pragma unroll
    for (int e=0;e<8;e++) v[e] = tile[rv+e][cr];
    *(u16x8*)&dst[(size_t)(c0+cr)*src_rows + r0 + rv] = v;
  }
}

// ---------------- V transpose: qkv[b,t, 2*2048 + h*128 + d] -> vt[bh][d][t] (bf16) ----------------
__global__ __launch_bounds__(256) void transpose_v(const u16* __restrict__ qkv, u16* __restrict__ vt)
{
  __shared__ u16 tile[64][72];
  const int bh = blockIdx.z;
  const int b = bh >> 4, h = bh & 15;
  const u16* src = qkv + (size_t)b*2048*6144 + 4096 + h*128;
  u16* dst = vt + (size_t)bh*128*2048;
  const int t0 = blockIdx.y << 6, d0 = blockIdx.x << 6;
  const int t = threadIdx.x;
  #pragma unroll
  for (int i=0;i<2;i++){
    int slot = t + (i<<8);
    int r = slot >> 3, cv = (slot & 7) << 3;
    *(u16x8*)&tile[r][cv] = *(const u16x8*)&src[(size_t)(t0+r)*6144 + d0 + cv];
  }
  __syncthreads();
  #pragma unroll
  for (int i=0;i<2;i++){
    int slot = t + (i<<8);
    int cr = slot >> 3, rv = (slot & 7) << 3;
    u16x8 v;
    #pragma unroll
    for (int e=0;e<8;e++) v[e] = tile[rv+e][cr];
    *(u16x8*)&dst[(size_t)(d0+cr)*2048 + t0 + rv] = v;
  }
}

// ---------------- GEMM C = A * Bt^T + bias (bf16 in, f32 accum) ----------------
template<int F32OUT>
__global__ __launch_bounds__(256) void gemm_bt(const u16* __restrict__ A, const u16* __restrict__ Bt,
                                               const float* __restrict__ bias, void* __restrict__ Cv,
                                               int M, int N, int K)
{
  __shared__ u16 lsA[128*32];
  __shared__ u16 lsB[128*32];
  const int tid = threadIdx.x;
  const int w = tid >> 6, lane = tid & 63;
  const int wm = w >> 1, wn = w & 1;
  const int m0 = blockIdx.y << 7, n0 = blockIdx.x << 7;
  const int lo = lane & 15, hi = lane >> 4;

  f32x4 acc[4][4];
  f32x4 z = {0.f,0.f,0.f,0.f};
  #pragma unroll
  for (int i=0;i<4;i++)
    #pragma unroll
    for (int j=0;j<4;j++) acc[i][j] = z;

  const int rA = lane >> 2;
  const int cA = (lane & 3) << 3;

  for (int k0 = 0; k0 < K; k0 += 32) {
    #pragma unroll
    for (int i=0;i<2;i++){
      int chunk = w + (i<<2);
      async16(A  + (size_t)(m0 + chunk*16 + rA)*K + k0 + cA, &lsA[chunk*512]);
      async16(Bt + (size_t)(n0 + chunk*16 + rA)*K + k0 + cA, &lsB[chunk*512]);
    }
    __syncthreads();
    bf16x8 af[4], bfr[4];
    #pragma unroll
    for (int i=0;i<4;i++) af[i]  = *(const bf16x8*)&lsA[(wm*64 + i*16 + lo)*32 + (hi<<3)];
    #pragma unroll
    for (int j=0;j<4;j++) bfr[j] = *(const bf16x8*)&lsB[(wn*64 + j*16 + lo)*32 + (hi<<3)];
    #pragma unroll
    for (int i=0;i<4;i++)
      #pragma unroll
      for (int j=0;j<4;j++)
        acc[i][j] = __builtin_amdgcn_mfma_f32_16x16x32_bf16(af[i], bfr[j], acc[i][j], 0,0,0);
    __syncthreads();
  }

  float bv[4];
  #pragma unroll
  for (int j=0;j<4;j++) bv[j] = bias[n0 + wn*64 + j*16 + lo];
  #pragma unroll
  for (int i=0;i<4;i++){
    int row = m0 + wm*64 + i*16 + (hi<<2);
    #pragma unroll
    for (int j=0;j<4;j++){
      int col = n0 + wn*64 + j*16 + lo;
      #pragma unroll
      for (int r=0;r<4;r++){
        float vv = acc[i][j][r] + bv[j];
        if (F32OUT) ((float*)Cv)[(size_t)(row+r)*N + col] = vv;
        else        ((u16*)Cv)[(size_t)(row+r)*N + col] = f2bf(vv);
      }
    }
  }
}

// ---------------- causal flash attention v4 ----------------
// grid: (8, B*H); block 512 = 8 waves, wave owns 16 q-rows. Triangle pairing:
// block handles q-tile (15-pair) then (pair) -> uniform work. K double-buffered
// in LDS (XOR-swizzled); V direct from global V^T (L2-resident); P per-wave
// LDS, XOR-swizzled.
__global__ __launch_bounds__(512, 4) void attn_fwd(const u16* __restrict__ qkv, const u16* __restrict__ vt,
                                                   u16* __restrict__ y)
{
  __shared__ u16 kb[2][64*128];    // K tile dbuf [krow][d], bytes ^= (krow&7)<<4
  __shared__ u16 plds[8][16*64];   // per-wave P [16 q][64 k], bytes ^= (qrow&7)<<4
  const int bh = blockIdx.y;
  const int b = bh >> 4, h = bh & 15;
  const int pair = blockIdx.x;     // 0..7
  const int tid = threadIdx.x;
  const int w = tid >> 6, lane = tid & 63;
  const int lo = lane & 15, hi = lane >> 4;

  const u16* Qb = qkv + (size_t)b*2048*6144 + h*128;
  const u16* Kb = Qb + 2048;
  const u16* Vb = vt + (size_t)bh*128*2048;   // [d][t]
  u16* pw = &plds[w][0];
  const float sc = 0.08838834764831845f * 1.4426950408889634f;  // 1/sqrt(128)*log2(e)
  f32x4 z = {0.f,0.f,0.f,0.f};

  #pragma unroll 1
  for (int seg = 0; seg < 2; ++seg){
    const int qt = seg ? pair : 15 - pair;
    const int qw = qt*128 + w*16;              // wave's first q-row
    const int nt = qt*2 + 2;

    bf16x8 qf[4];
    #pragma unroll
    for (int kd=0;kd<4;kd++)
      qf[kd] = *(const bf16x8*)&Qb[(size_t)(qw + lo)*6144 + kd*32 + hi*8];

    f32x4 o[8];
    #pragma unroll
    for (int dj=0;dj<8;dj++) o[dj] = z;
    float mx[4], lsum[4];
    #pragma unroll
    for (int r=0;r<4;r++){ mx[r] = -3.0e38f; lsum[r] = 0.f; }

    // prologue: stage tile 0 into kb[0] (512 thr x 2 x 16B = 16KB)
    #pragma unroll
    for (int i=0;i<2;i++){
      int slot = i*512 + tid;
      int kr = slot >> 4;
      int kc = ((slot & 15) << 4) ^ ((kr & 7) << 4);
      async16(Kb + (size_t)kr*6144 + (kc >> 1), &kb[0][(size_t)(i*512 + w*64)*8]);
    }
    __syncthreads();

    #pragma unroll 1
    for (int it = 0; it < nt; ++it){
      const int k0 = it*64;
      if (it + 1 < nt){
        const int kn = (it+1)*64;
        u16* dst = kb[(it+1)&1];
        #pragma unroll
        for (int i=0;i<2;i++){
          int slot = i*512 + tid;
          int kr = slot >> 4;
          int kc = ((slot & 15) << 4) ^ ((kr & 7) << 4);
          async16(Kb + (size_t)(kn + kr)*6144 + (kc >> 1), &dst[(size_t)(i*512 + w*64)*8]);
        }
      }
      if (k0 <= qw + 15){
        const u16* kcur = kb[it&1];
        // ---- QK^T: S[16q x 64k] (raw, scale folded into exp) ----
        f32x4 s[4];
        #pragma unroll
        for (int t=0;t<4;t++) s[t] = z;
        __builtin_amdgcn_s_setprio(1);
        #pragma unroll
        for (int t=0;t<4;t++){
          #pragma unroll
          for (int kd=0;kd<4;kd++){
            int row = t*16 + lo;
            int cb = (kd*64 + hi*16) ^ ((lo & 7) << 4);
            bf16x8 kk = *(const bf16x8*)&kcur[row*128 + (cb >> 1)];
            s[t] = __builtin_amdgcn_mfma_f32_16x16x32_bf16(qf[kd], kk, s[t], 0,0,0);
          }
        }
        __builtin_amdgcn_s_setprio(0);

        // ---- causal mask + online softmax ----
        if (k0 + 63 > qw) {
          #pragma unroll
          for (int t=0;t<4;t++)
            #pragma unroll
            for (int r=0;r<4;r++){
              int q = qw + hi*4 + r;
              int k = k0 + t*16 + lo;
              if (k > q) s[t][r] = -3.0e38f;
            }
        }
        #pragma unroll
        for (int r=0;r<4;r++){
          float tm = fmaxf(fmaxf(s[0][r], s[1][r]), fmaxf(s[2][r], s[3][r]));
          tm = fmaxf(tm, __shfl_xor(tm, 1));
          tm = fmaxf(tm, __shfl_xor(tm, 2));
          tm = fmaxf(tm, __shfl_xor(tm, 4));
          tm = fmaxf(tm, __shfl_xor(tm, 8));
          tm *= sc;
          float mn = fmaxf(mx[r], tm);
          float al = exp2f(mx[r] - mn);
          mx[r] = mn;
          float p0 = exp2f(fmaf(s[0][r], sc, -mn));
          float p1 = exp2f(fmaf(s[1][r], sc, -mn));
          float p2 = exp2f(fmaf(s[2][r], sc, -mn));
          float p3 = exp2f(fmaf(s[3][r], sc, -mn));
          float sum = (p0 + p1) + (p2 + p3);
          sum += __shfl_xor(sum, 1);
          sum += __shfl_xor(sum, 2);
          sum += __shfl_xor(sum, 4);
          sum += __shfl_xor(sum, 8);
          lsum[r] = lsum[r]*al + sum;
          #pragma unroll
          for (int dj=0;dj<8;dj++) o[dj][r] *= al;
          int row = hi*4 + r;
          int sw = (row & 7) << 4;
          u16* prow = pw + row*64;
          prow[((     lo*2) ^ sw) >> 1] = f2bf(p0);
          prow[((32 + lo*2) ^ sw) >> 1] = f2bf(p1);
          prow[((64 + lo*2) ^ sw) >> 1] = f2bf(p2);
          prow[((96 + lo*2) ^ sw) >> 1] = f2bf(p3);
        }

        // ---- PV: O += P[16x64] * V[64x128], V direct from global V^T ----
        bf16x8 pa[2];
        #pragma unroll
        for (int kf=0;kf<2;kf++)
          pa[kf] = *(const bf16x8*)&pw[(lo*128 + ((kf*64 + hi*16) ^ ((lo & 7) << 4))) >> 1];
        __builtin_amdgcn_s_setprio(1);
        #pragma unroll
        for (int dj=0;dj<8;dj++){
          const u16* vr = &Vb[(size_t)(dj*16 + lo)*2048 + k0];
          bf16x8 vv0 = *(const bf16x8*)&vr[hi*8];
          bf16x8 vv1 = *(const bf16x8*)&vr[32 + hi*8];
          o[dj] = __builtin_amdgcn_mfma_f32_16x16x32_bf16(pa[0], vv0, o[dj], 0,0,0);
          o[dj] = __builtin_amdgcn_mfma_f32_16x16x32_bf16(pa[1], vv1, o[dj], 0,0,0);
        }
        __builtin_amdgcn_s_setprio(0);
      }
      __syncthreads();   // drains stage loads (vmcnt) + releases kb[it&1]
    }

    // ---- epilogue ----
    #pragma unroll
    for (int r=0;r<4;r++){
      float inv = 1.0f / lsum[r];
      size_t row = (size_t)(b*2048 + qw + hi*4 + r);
      #pragma unroll
      for (int dj=0;dj<8;dj++)
        y[row*2048 + h*128 + dj*16 + lo] = f2bf(o[dj][r] * inv);
    }
    __syncthreads();   // keep segments separated (kb reuse)
  }
}

extern "C" void kernel_launch(void* const* d_in, const int* in_sizes, int n_in,
                              void* d_out, int out_size, void* d_ws, size_t ws_size,
                              hipStream_t stream) {
  (void)in_sizes; (void)n_in; (void)out_size; (void)ws_size;
  const float* x      = (const float*)d_in[0];  // [8192][2048] f32
  const float* w_attn = (const float*)d_in[1];  // [2048][6144] f32
  const float* b_attn = (const float*)d_in[2];  // [6144] f32
  const float* w_proj = (const float*)d_in[3];  // [2048][2048] f32
  const float* b_proj = (const float*)d_in[4];  // [2048] f32
  float* out = (float*)d_out;                   // [8192][2048] f32

  char* ws = (char*)d_ws;
  u16* xbf = (u16*)(ws);                     // [8192][2048] bf16, 32 MB; reused as y
  u16* wT  = (u16*)(ws + 33554432);          // [6144][2048] bf16, 24 MB
  u16* pT  = (u16*)(ws + 58720256);          // [2048][2048] bf16,  8 MB
  u16* qkv = (u16*)(ws + 67108864);          // [8192][6144] bf16, 96 MB
  u16* vt  = (u16*)(ws + 167772160);         // [64][128][2048] bf16, 32 MB
  u16* y   = xbf;

  cvt_f2b<<<16384, 256, 0, stream>>>(x, xbf, 8192*2048);
  transpose2d_f2b<<<dim3(96,32), 256, 0, stream>>>(w_attn, wT, 2048, 6144);
  transpose2d_f2b<<<dim3(32,32), 256, 0, stream>>>(w_proj, pT, 2048, 2048);
  gemm_bt<0><<<dim3(48,64), 256, 0, stream>>>(xbf, wT, b_attn, qkv, 8192, 6144, 2048);
  transpose_v<<<dim3(2,32,64), 256, 0, stream>>>(qkv, vt);
  attn_fwd<<<dim3(8,64), 512, 0, stream>>>(qkv, vt, y);
  gemm_bt<1><<<dim3(16,64), 256, 0, stream>>>(y, pT, b_proj, out, 8192, 2048, 2048);
}

// Round 6
// 604.202 us; speedup vs baseline: 2.1457x; 1.2132x over previous
//
#include <hip/hip_runtime.h>
#include <hip/hip_bf16.h>
#include <stdint.h>

typedef unsigned short u16;
typedef __bf16 bf16x8 __attribute__((ext_vector_type(8)));
typedef unsigned short u16x8 __attribute__((ext_vector_type(8)));
typedef float f32x4 __attribute__((ext_vector_type(4)));

__device__ __forceinline__ float bf2f(u16 u){ union{float f; unsigned i;} v; v.i = ((unsigned)u)<<16; return v.f; }
__device__ __forceinline__ u16 f2bf(float f){ union{float f; unsigned i;} v; v.f=f; unsigned r = v.i + 0x7FFFu + ((v.i>>16)&1u); return (u16)(r>>16); }

__device__ __forceinline__ void async16(const void* g, void* l){
  __builtin_amdgcn_global_load_lds((const __attribute__((address_space(1))) void*)g,
                                   (__attribute__((address_space(3))) void*)l, 16, 0, 0);
}

// ---------------- f32 -> bf16 elementwise cast (vectorized) ----------------
__global__ __launch_bounds__(256) void cvt_f2b(const float* __restrict__ src, u16* __restrict__ dst, int n)
{
  int i = (blockIdx.x * 256 + threadIdx.x) * 4;
  if (i < n) {
    float4 v = *(const float4*)&src[i];
    ushort4 o;
    o.x = f2bf(v.x); o.y = f2bf(v.y); o.z = f2bf(v.z); o.w = f2bf(v.w);
    *(ushort4*)&dst[i] = o;
  }
}

// ---------------- f32 src -> bf16 transposed dst, 64x64 tiles ----------------
__global__ __launch_bounds__(256) void transpose2d_f2b(const float* __restrict__ src, u16* __restrict__ dst,
                                                       int src_rows, int src_cols)
{
  __shared__ u16 tile[64][72];
  const int r0 = blockIdx.y << 6, c0 = blockIdx.x << 6;
  const int t = threadIdx.x;
  #pragma unroll
  for (int i=0;i<4;i++){
    int slot = t + (i<<8);
    int r = slot >> 4, cv = (slot & 15) << 2;
    float4 v = *(const float4*)&src[(size_t)(r0+r)*src_cols + c0 + cv];
    tile[r][cv+0] = f2bf(v.x); tile[r][cv+1] = f2bf(v.y);
    tile[r][cv+2] = f2bf(v.z); tile[r][cv+3] = f2bf(v.w);
  }
  __syncthreads();
  #pragma unroll
  for (int i=0;i<2;i++){
    int slot = t + (i<<8);
    int cr = slot >> 3, rv = (slot & 7) << 3;
    u16x8 v;
    #pragma unroll
    for (int e=0;e<8;e++) v[e] = tile[rv+e][cr];
    *(u16x8*)&dst[(size_t)(c0+cr)*src_rows + r0 + rv] = v;
  }
}

// ---------------- V transpose: qkv[b,t, 2*2048 + h*128 + d] -> vt[bh][d][t] (bf16) ----------------
__global__ __launch_bounds__(256) void transpose_v(const u16* __restrict__ qkv, u16* __restrict__ vt)
{
  __shared__ u16 tile[64][72];
  const int bh = blockIdx.z;
  const int b = bh >> 4, h = bh & 15;
  const u16* src = qkv + (size_t)b*2048*6144 + 4096 + h*128;
  u16* dst = vt + (size_t)bh*128*2048;
  const int t0 = blockIdx.y << 6, d0 = blockIdx.x << 6;
  const int t = threadIdx.x;
  #pragma unroll
  for (int i=0;i<2;i++){
    int slot = t + (i<<8);
    int r = slot >> 3, cv = (slot & 7) << 3;
    *(u16x8*)&tile[r][cv] = *(const u16x8*)&src[(size_t)(t0+r)*6144 + d0 + cv];
  }
  __syncthreads();
  #pragma unroll
  for (int i=0;i<2;i++){
    int slot = t + (i<<8);
    int cr = slot >> 3, rv = (slot & 7) << 3;
    u16x8 v;
    #pragma unroll
    for (int e=0;e<8;e++) v[e] = tile[rv+e][cr];
    *(u16x8*)&dst[(size_t)(d0+cr)*2048 + t0 + rv] = v;
  }
}

// ---------------- GEMM C = A * Bt^T + bias (bf16 in, f32 accum) ----------------
template<int F32OUT>
__global__ __launch_bounds__(256) void gemm_bt(const u16* __restrict__ A, const u16* __restrict__ Bt,
                                               const float* __restrict__ bias, void* __restrict__ Cv,
                                               int M, int N, int K)
{
  __shared__ u16 lsA[128*32];
  __shared__ u16 lsB[128*32];
  const int tid = threadIdx.x;
  const int w = tid >> 6, lane = tid & 63;
  const int wm = w >> 1, wn = w & 1;
  const int m0 = blockIdx.y << 7, n0 = blockIdx.x << 7;
  const int lo = lane & 15, hi = lane >> 4;

  f32x4 acc[4][4];
  f32x4 z = {0.f,0.f,0.f,0.f};
  #pragma unroll
  for (int i=0;i<4;i++)
    #pragma unroll
    for (int j=0;j<4;j++) acc[i][j] = z;

  const int rA = lane >> 2;
  const int cA = (lane & 3) << 3;

  for (int k0 = 0; k0 < K; k0 += 32) {
    #pragma unroll
    for (int i=0;i<2;i++){
      int chunk = w + (i<<2);
      async16(A  + (size_t)(m0 + chunk*16 + rA)*K + k0 + cA, &lsA[chunk*512]);
      async16(Bt + (size_t)(n0 + chunk*16 + rA)*K + k0 + cA, &lsB[chunk*512]);
    }
    __syncthreads();
    bf16x8 af[4], bfr[4];
    #pragma unroll
    for (int i=0;i<4;i++) af[i]  = *(const bf16x8*)&lsA[(wm*64 + i*16 + lo)*32 + (hi<<3)];
    #pragma unroll
    for (int j=0;j<4;j++) bfr[j] = *(const bf16x8*)&lsB[(wn*64 + j*16 + lo)*32 + (hi<<3)];
    #pragma unroll
    for (int i=0;i<4;i++)
      #pragma unroll
      for (int j=0;j<4;j++)
        acc[i][j] = __builtin_amdgcn_mfma_f32_16x16x32_bf16(af[i], bfr[j], acc[i][j], 0,0,0);
    __syncthreads();
  }

  float bv[4];
  #pragma unroll
  for (int j=0;j<4;j++) bv[j] = bias[n0 + wn*64 + j*16 + lo];
  #pragma unroll
  for (int i=0;i<4;i++){
    int row = m0 + wm*64 + i*16 + (hi<<2);
    #pragma unroll
    for (int j=0;j<4;j++){
      int col = n0 + wn*64 + j*16 + lo;
      #pragma unroll
      for (int r=0;r<4;r++){
        float vv = acc[i][j][r] + bv[j];
        if (F32OUT) ((float*)Cv)[(size_t)(row+r)*N + col] = vv;
        else        ((u16*)Cv)[(size_t)(row+r)*N + col] = f2bf(vv);
      }
    }
  }
}

// ---------------- causal flash attention v5 ----------------
// grid: (8, B*H); block 512 = 8 waves, wave owns 16 q-rows. Triangle pairing.
// K AND V double-buffered in LDS via global_load_lds (XOR-swizzled); P per-wave
// LDS, XOR-swizzled. LDS = 80 KB -> exactly 2 blocks/CU.
__global__ __launch_bounds__(512, 4) void attn_fwd(const u16* __restrict__ qkv, const u16* __restrict__ vt,
                                                   u16* __restrict__ y)
{
  __shared__ u16 kb[2][64*128];    // K tile dbuf [krow][d], bytes ^= (krow&7)<<4
  __shared__ u16 vb[2][128*64];    // V tile dbuf [d][kcol], bytes ^= (d&7)<<4
  __shared__ u16 plds[8][16*64];   // per-wave P [16 q][64 k], bytes ^= (qrow&7)<<4
  const int bh = blockIdx.y;
  const int b = bh >> 4, h = bh & 15;
  const int pair = blockIdx.x;     // 0..7
  const int tid = threadIdx.x;
  const int w = tid >> 6, lane = tid & 63;
  const int lo = lane & 15, hi = lane >> 4;

  const u16* Qb = qkv + (size_t)b*2048*6144 + h*128;
  const u16* Kb = Qb + 2048;
  const u16* Vb = vt + (size_t)bh*128*2048;   // [d][t]
  u16* pw = &plds[w][0];
  const float sc = 0.08838834764831845f * 1.4426950408889634f;  // 1/sqrt(128)*log2(e)
  f32x4 z = {0.f,0.f,0.f,0.f};

  #pragma unroll 1
  for (int seg = 0; seg < 2; ++seg){
    const int qt = seg ? pair : 15 - pair;
    const int qw = qt*128 + w*16;              // wave's first q-row
    const int nt = qt*2 + 2;

    bf16x8 qf[4];
    #pragma unroll
    for (int kd=0;kd<4;kd++)
      qf[kd] = *(const bf16x8*)&Qb[(size_t)(qw + lo)*6144 + kd*32 + hi*8];

    f32x4 o[8];
    #pragma unroll
    for (int dj=0;dj<8;dj++) o[dj] = z;
    float mx[4], lsum[4];
    #pragma unroll
    for (int r=0;r<4;r++){ mx[r] = -3.0e38f; lsum[r] = 0.f; }

    // prologue: stage K+V tile 0 into buf 0
    #pragma unroll
    for (int i=0;i<2;i++){
      int slot = i*512 + tid;
      int kr = slot >> 4;
      int kc = ((slot & 15) << 4) ^ ((kr & 7) << 4);
      async16(Kb + (size_t)kr*6144 + (kc >> 1), &kb[0][(size_t)(i*512 + w*64)*8]);
      int vr = slot >> 3;
      int vc = ((slot & 7) << 4) ^ ((vr & 7) << 4);
      async16(Vb + (size_t)vr*2048 + (vc >> 1), &vb[0][(size_t)(i*512 + w*64)*8]);
    }
    __syncthreads();

    #pragma unroll 1
    for (int it = 0; it < nt; ++it){
      const int k0 = it*64;
      if (it + 1 < nt){
        const int kn = (it+1)*64;
        u16* kdst = kb[(it+1)&1];
        u16* vdst = vb[(it+1)&1];
        #pragma unroll
        for (int i=0;i<2;i++){
          int slot = i*512 + tid;
          int kr = slot >> 4;
          int kc = ((slot & 15) << 4) ^ ((kr & 7) << 4);
          async16(Kb + (size_t)(kn + kr)*6144 + (kc >> 1), &kdst[(size_t)(i*512 + w*64)*8]);
          int vr = slot >> 3;
          int vc = ((slot & 7) << 4) ^ ((vr & 7) << 4);
          async16(Vb + (size_t)vr*2048 + kn + (vc >> 1), &vdst[(size_t)(i*512 + w*64)*8]);
        }
      }
      if (k0 <= qw + 15){
        const u16* kcur = kb[it&1];
        const u16* vcur = vb[it&1];
        // ---- QK^T: S[16q x 64k] (raw, scale folded into exp) ----
        f32x4 s[4];
        #pragma unroll
        for (int t=0;t<4;t++) s[t] = z;
        __builtin_amdgcn_s_setprio(1);
        #pragma unroll
        for (int t=0;t<4;t++){
          #pragma unroll
          for (int kd=0;kd<4;kd++){
            int row = t*16 + lo;
            int cb = (kd*64 + hi*16) ^ ((lo & 7) << 4);
            bf16x8 kk = *(const bf16x8*)&kcur[row*128 + (cb >> 1)];
            s[t] = __builtin_amdgcn_mfma_f32_16x16x32_bf16(qf[kd], kk, s[t], 0,0,0);
          }
        }
        __builtin_amdgcn_s_setprio(0);

        // ---- causal mask + online softmax ----
        if (k0 + 63 > qw) {
          #pragma unroll
          for (int t=0;t<4;t++)
            #pragma unroll
            for (int r=0;r<4;r++){
              int q = qw + hi*4 + r;
              int k = k0 + t*16 + lo;
              if (k > q) s[t][r] = -3.0e38f;
            }
        }
        #pragma unroll
        for (int r=0;r<4;r++){
          float tm = fmaxf(fmaxf(s[0][r], s[1][r]), fmaxf(s[2][r], s[3][r]));
          tm = fmaxf(tm, __shfl_xor(tm, 1));
          tm = fmaxf(tm, __shfl_xor(tm, 2));
          tm = fmaxf(tm, __shfl_xor(tm, 4));
          tm = fmaxf(tm, __shfl_xor(tm, 8));
          tm *= sc;
          float mn = fmaxf(mx[r], tm);
          float al = exp2f(mx[r] - mn);
          mx[r] = mn;
          float p0 = exp2f(fmaf(s[0][r], sc, -mn));
          float p1 = exp2f(fmaf(s[1][r], sc, -mn));
          float p2 = exp2f(fmaf(s[2][r], sc, -mn));
          float p3 = exp2f(fmaf(s[3][r], sc, -mn));
          float sum = (p0 + p1) + (p2 + p3);
          sum += __shfl_xor(sum, 1);
          sum += __shfl_xor(sum, 2);
          sum += __shfl_xor(sum, 4);
          sum += __shfl_xor(sum, 8);
          lsum[r] = lsum[r]*al + sum;
          #pragma unroll
          for (int dj=0;dj<8;dj++) o[dj][r] *= al;
          int row = hi*4 + r;
          int sw = (row & 7) << 4;
          u16* prow = pw + row*64;
          prow[((     lo*2) ^ sw) >> 1] = f2bf(p0);
          prow[((32 + lo*2) ^ sw) >> 1] = f2bf(p1);
          prow[((64 + lo*2) ^ sw) >> 1] = f2bf(p2);
          prow[((96 + lo*2) ^ sw) >> 1] = f2bf(p3);
        }

        // ---- PV: O += P[16x64] * V[64x128], V from LDS (swizzled) ----
        bf16x8 pa[2];
        #pragma unroll
        for (int kf=0;kf<2;kf++)
          pa[kf] = *(const bf16x8*)&pw[(lo*128 + ((kf*64 + hi*16) ^ ((lo & 7) << 4))) >> 1];
        __builtin_amdgcn_s_setprio(1);
        #pragma unroll
        for (int dj=0;dj<8;dj++){
          int row = dj*16 + lo;
          int cb0 = (hi*16)      ^ ((lo & 7) << 4);
          int cb1 = (64 + hi*16) ^ ((lo & 7) << 4);
          bf16x8 vv0 = *(const bf16x8*)&vcur[row*64 + (cb0 >> 1)];
          bf16x8 vv1 = *(const bf16x8*)&vcur[row*64 + (cb1 >> 1)];
          o[dj] = __builtin_amdgcn_mfma_f32_16x16x32_bf16(pa[0], vv0, o[dj], 0,0,0);
          o[dj] = __builtin_amdgcn_mfma_f32_16x16x32_bf16(pa[1], vv1, o[dj], 0,0,0);
        }
        __builtin_amdgcn_s_setprio(0);
      }
      __syncthreads();   // drains stage loads (vmcnt) + releases buffers
    }

    // ---- epilogue ----
    #pragma unroll
    for (int r=0;r<4;r++){
      float inv = 1.0f / lsum[r];
      size_t row = (size_t)(b*2048 + qw + hi*4 + r);
      #pragma unroll
      for (int dj=0;dj<8;dj++)
        y[row*2048 + h*128 + dj*16 + lo] = f2bf(o[dj][r] * inv);
    }
    __syncthreads();   // keep segments separated (kb/vb reuse)
  }
}

extern "C" void kernel_launch(void* const* d_in, const int* in_sizes, int n_in,
                              void* d_out, int out_size, void* d_ws, size_t ws_size,
                              hipStream_t stream) {
  (void)in_sizes; (void)n_in; (void)out_size; (void)ws_size;
  const float* x      = (const float*)d_in[0];  // [8192][2048] f32
  const float* w_attn = (const float*)d_in[1];  // [2048][6144] f32
  const float* b_attn = (const float*)d_in[2];  // [6144] f32
  const float* w_proj = (const float*)d_in[3];  // [2048][2048] f32
  const float* b_proj = (const float*)d_in[4];  // [2048] f32
  float* out = (float*)d_out;                   // [8192][2048] f32

  char* ws = (char*)d_ws;
  u16* xbf = (u16*)(ws);                     // [8192][2048] bf16, 32 MB; reused as y
  u16* wT  = (u16*)(ws + 33554432);          // [6144][2048] bf16, 24 MB
  u16* pT  = (u16*)(ws + 58720256);          // [2048][2048] bf16,  8 MB
  u16* qkv = (u16*)(ws + 67108864);          // [8192][6144] bf16, 96 MB
  u16* vt  = (u16*)(ws + 167772160);         // [64][128][2048] bf16, 32 MB
  u16* y   = xbf;

  cvt_f2b<<<16384, 256, 0, stream>>>(x, xbf, 8192*2048);
  transpose2d_f2b<<<dim3(96,32), 256, 0, stream>>>(w_attn, wT, 2048, 6144);
  transpose2d_f2b<<<dim3(32,32), 256, 0, stream>>>(w_proj, pT, 2048, 2048);
  gemm_bt<0><<<dim3(48,64), 256, 0, stream>>>(xbf, wT, b_attn, qkv, 8192, 6144, 2048);
  transpose_v<<<dim3(2,32,64), 256, 0, stream>>>(qkv, vt);
  attn_fwd<<<dim3(8,64), 512, 0, stream>>>(qkv, vt, y);
  gemm_bt<1><<<dim3(16,64), 256, 0, stream>>>(y, pT, b_proj, out, 8192, 2048, 2048);
}

// Round 7
// 603.556 us; speedup vs baseline: 2.1480x; 1.0011x over previous
//
#include <hip/hip_runtime.h>
#include <hip/hip_bf16.h>
#include <stdint.h>

typedef unsigned short u16;
typedef __bf16 bf16x8 __attribute__((ext_vector_type(8)));
typedef unsigned short u16x8 __attribute__((ext_vector_type(8)));
typedef float f32x4 __attribute__((ext_vector_type(4)));

__device__ __forceinline__ float bf2f(u16 u){ union{float f; unsigned i;} v; v.i = ((unsigned)u)<<16; return v.f; }
__device__ __forceinline__ u16 f2bf(float f){ union{float f; unsigned i;} v; v.f=f; unsigned r = v.i + 0x7FFFu + ((v.i>>16)&1u); return (u16)(r>>16); }

__device__ __forceinline__ void async16(const void* g, void* l){
  __builtin_amdgcn_global_load_lds((const __attribute__((address_space(1))) void*)g,
                                   (__attribute__((address_space(3))) void*)l, 16, 0, 0);
}

// ---------------- f32 -> bf16 elementwise cast (vectorized) ----------------
__global__ __launch_bounds__(256) void cvt_f2b(const float* __restrict__ src, u16* __restrict__ dst, int n)
{
  int i = (blockIdx.x * 256 + threadIdx.x) * 4;
  if (i < n) {
    float4 v = *(const float4*)&src[i];
    ushort4 o;
    o.x = f2bf(v.x); o.y = f2bf(v.y); o.z = f2bf(v.z); o.w = f2bf(v.w);
    *(ushort4*)&dst[i] = o;
  }
}

// ---------------- f32 src -> bf16 transposed dst, 64x64 tiles ----------------
__global__ __launch_bounds__(256) void transpose2d_f2b(const float* __restrict__ src, u16* __restrict__ dst,
                                                       int src_rows, int src_cols)
{
  __shared__ u16 tile[64][72];
  const int r0 = blockIdx.y << 6, c0 = blockIdx.x << 6;
  const int t = threadIdx.x;
  #pragma unroll
  for (int i=0;i<4;i++){
    int slot = t + (i<<8);
    int r = slot >> 4, cv = (slot & 15) << 2;
    float4 v = *(const float4*)&src[(size_t)(r0+r)*src_cols + c0 + cv];
    tile[r][cv+0] = f2bf(v.x); tile[r][cv+1] = f2bf(v.y);
    tile[r][cv+2] = f2bf(v.z); tile[r][cv+3] = f2bf(v.w);
  }
  __syncthreads();
  #pragma unroll
  for (int i=0;i<2;i++){
    int slot = t + (i<<8);
    int cr = slot >> 3, rv = (slot & 7) << 3;
    u16x8 v;
    #pragma unroll
    for (int e=0;e<8;e++) v[e] = tile[rv+e][cr];
    *(u16x8*)&dst[(size_t)(c0+cr)*src_rows + r0 + rv] = v;
  }
}

// ---------------- V transpose: qkv[b,t, 2*2048 + h*128 + d] -> vt[bh][d][t] (bf16) ----------------
__global__ __launch_bounds__(256) void transpose_v(const u16* __restrict__ qkv, u16* __restrict__ vt)
{
  __shared__ u16 tile[64][72];
  const int bh = blockIdx.z;
  const int b = bh >> 4, h = bh & 15;
  const u16* src = qkv + (size_t)b*2048*6144 + 4096 + h*128;
  u16* dst = vt + (size_t)bh*128*2048;
  const int t0 = blockIdx.y << 6, d0 = blockIdx.x << 6;
  const int t = threadIdx.x;
  #pragma unroll
  for (int i=0;i<2;i++){
    int slot = t + (i<<8);
    int r = slot >> 3, cv = (slot & 7) << 3;
    *(u16x8*)&tile[r][cv] = *(const u16x8*)&src[(size_t)(t0+r)*6144 + d0 + cv];
  }
  __syncthreads();
  #pragma unroll
  for (int i=0;i<2;i++){
    int slot = t + (i<<8);
    int cr = slot >> 3, rv = (slot & 7) << 3;
    u16x8 v;
    #pragma unroll
    for (int e=0;e<8;e++) v[e] = tile[rv+e][cr];
    *(u16x8*)&dst[(size_t)(d0+cr)*2048 + t0 + rv] = v;
  }
}

// ---------------- GEMM v2: C = A * Bt^T + bias, deep-pipelined ----------------
// BM=128, BN=256, BK=64, 512 thr / 8 waves (2x4), wave out 64x64.
// 3-buffer LDS ring (144 KB), counted vmcnt(6), raw barriers, XOR-swizzled LDS,
// setprio around MFMA clusters, bijective XCD swizzle (m-fastest).
template<int F32OUT>
__global__ __launch_bounds__(512) void gemm_bt2(const u16* __restrict__ A, const u16* __restrict__ Bt,
                                                const float* __restrict__ bias, void* __restrict__ Cv,
                                                int M, int N, int K, int mtiles)
{
  __shared__ u16 lsA[3][128*64];   // rows: 128B, bytes ^= (row&7)<<4
  __shared__ u16 lsB[3][256*64];
  const int tid = threadIdx.x;
  const int w = tid >> 6, lane = tid & 63;
  const int wm = w >> 2, wn = w & 3;
  const int lo = lane & 15, hi = lane >> 4;

  // bijective XCD swizzle (grid multiple of 8), then m-fastest decomposition
  const int nwg = gridDim.x;
  const int bid = blockIdx.x;
  const int swz = (bid & 7) * (nwg >> 3) + (bid >> 3);
  const int mt = swz % mtiles, nt = swz / mtiles;
  const int m0 = mt << 7, n0 = nt << 8;
  const int NT = K >> 6;

  // stage address precompute (element units). slot s: row = s>>3, granule = s&7,
  // source col granule = (g ^ (row&7)) -> linear LDS dest stays inverse-swizzled.
  int rA[2], cA[2], rB[4], cB[4];
  #pragma unroll
  for (int i=0;i<2;i++){ int s = tid + i*512; int row = s>>3, g = s&7; rA[i]=row; cA[i]=(g^(row&7))*8; }
  #pragma unroll
  for (int i=0;i<4;i++){ int s = tid + i*512; int row = s>>3, g = s&7; rB[i]=row; cB[i]=(g^(row&7))*8; }

  const u16* Arow = A + (size_t)m0*K;
  const u16* Brow = Bt + (size_t)n0*K;

  f32x4 acc[4][4];
  f32x4 z = {0.f,0.f,0.f,0.f};
  #pragma unroll
  for (int i=0;i<4;i++)
    #pragma unroll
    for (int j=0;j<4;j++) acc[i][j] = z;

  auto STAGE = [&](int t){
    const u16* Ab = Arow + t*64;
    const u16* Bb = Brow + t*64;
    u16* la = &lsA[t%3][0];
    u16* lb = &lsB[t%3][0];
    #pragma unroll
    for (int i=0;i<2;i++) async16(Ab + (size_t)rA[i]*K + cA[i], la + (tid + i*512)*8);
    #pragma unroll
    for (int i=0;i<4;i++) async16(Bb + (size_t)rB[i]*K + cB[i], lb + (tid + i*512)*8);
  };

  // prologue: stage tiles 0,1 (12 loads out); wait tile 0 (6 remain)
  STAGE(0);
  STAGE(1);
  asm volatile("s_waitcnt vmcnt(6)" ::: "memory");
  __builtin_amdgcn_s_barrier();
  __builtin_amdgcn_sched_barrier(0);

  for (int t = 0; t < NT; ++t){
    if (t + 2 < NT) STAGE(t + 2);    // dest buffer freed at end of tile t-1
    const u16* la = &lsA[t%3][0];
    const u16* lb = &lsB[t%3][0];
    #pragma unroll
    for (int ks=0; ks<2; ++ks){
      bf16x8 a[4], b[4];
      #pragma unroll
      for (int f=0;f<4;f++){
        int ra = wm*64 + f*16 + lo;
        a[f] = *(const bf16x8*)&la[ra*64 + (((ks*4 + hi) ^ (lo & 7)) * 8)];
        int rb = wn*64 + f*16 + lo;
        b[f] = *(const bf16x8*)&lb[rb*64 + (((ks*4 + hi) ^ (lo & 7)) * 8)];
      }
      __builtin_amdgcn_s_setprio(1);
      #pragma unroll
      for (int i=0;i<4;i++)
        #pragma unroll
        for (int j=0;j<4;j++)
          acc[i][j] = __builtin_amdgcn_mfma_f32_16x16x32_bf16(a[i], b[j], acc[i][j], 0,0,0);
      __builtin_amdgcn_s_setprio(0);
    }
    // gate next tile: counted wait, never 0 in steady state
    if (t + 2 < NT)      { asm volatile("s_waitcnt vmcnt(6)" ::: "memory"); }
    else if (t + 1 < NT) { asm volatile("s_waitcnt vmcnt(0)" ::: "memory"); }
    __builtin_amdgcn_s_barrier();
    __builtin_amdgcn_sched_barrier(0);
  }

  float bv[4];
  #pragma unroll
  for (int j=0;j<4;j++) bv[j] = bias[n0 + wn*64 + j*16 + lo];
  #pragma unroll
  for (int i=0;i<4;i++){
    int row = m0 + wm*64 + i*16 + (hi<<2);
    #pragma unroll
    for (int j=0;j<4;j++){
      int col = n0 + wn*64 + j*16 + lo;
      #pragma unroll
      for (int r=0;r<4;r++){
        float vv = acc[i][j][r] + bv[j];
        if (F32OUT) ((float*)Cv)[(size_t)(row+r)*N + col] = vv;
        else        ((u16*)Cv)[(size_t)(row+r)*N + col] = f2bf(vv);
      }
    }
  }
}

// ---------------- causal flash attention (v5, unchanged) ----------------
__global__ __launch_bounds__(512, 4) void attn_fwd(const u16* __restrict__ qkv, const u16* __restrict__ vt,
                                                   u16* __restrict__ y)
{
  __shared__ u16 kb[2][64*128];    // K tile dbuf [krow][d], bytes ^= (krow&7)<<4
  __shared__ u16 vb[2][128*64];    // V tile dbuf [d][kcol], bytes ^= (d&7)<<4
  __shared__ u16 plds[8][16*64];   // per-wave P [16 q][64 k], bytes ^= (qrow&7)<<4
  const int bh = blockIdx.y;
  const int b = bh >> 4, h = bh & 15;
  const int pair = blockIdx.x;
  const int tid = threadIdx.x;
  const int w = tid >> 6, lane = tid & 63;
  const int lo = lane & 15, hi = lane >> 4;

  const u16* Qb = qkv + (size_t)b*2048*6144 + h*128;
  const u16* Kb = Qb + 2048;
  const u16* Vb = vt + (size_t)bh*128*2048;
  u16* pw = &plds[w][0];
  const float sc = 0.08838834764831845f * 1.4426950408889634f;
  f32x4 z = {0.f,0.f,0.f,0.f};

  #pragma unroll 1
  for (int seg = 0; seg < 2; ++seg){
    const int qt = seg ? pair : 15 - pair;
    const int qw = qt*128 + w*16;
    const int nt = qt*2 + 2;

    bf16x8 qf[4];
    #pragma unroll
    for (int kd=0;kd<4;kd++)
      qf[kd] = *(const bf16x8*)&Qb[(size_t)(qw + lo)*6144 + kd*32 + hi*8];

    f32x4 o[8];
    #pragma unroll
    for (int dj=0;dj<8;dj++) o[dj] = z;
    float mx[4], lsum[4];
    #pragma unroll
    for (int r=0;r<4;r++){ mx[r] = -3.0e38f; lsum[r] = 0.f; }

    #pragma unroll
    for (int i=0;i<2;i++){
      int slot = i*512 + tid;
      int kr = slot >> 4;
      int kc = ((slot & 15) << 4) ^ ((kr & 7) << 4);
      async16(Kb + (size_t)kr*6144 + (kc >> 1), &kb[0][(size_t)(i*512 + w*64)*8]);
      int vr = slot >> 3;
      int vc = ((slot & 7) << 4) ^ ((vr & 7) << 4);
      async16(Vb + (size_t)vr*2048 + (vc >> 1), &vb[0][(size_t)(i*512 + w*64)*8]);
    }
    __syncthreads();

    #pragma unroll 1
    for (int it = 0; it < nt; ++it){
      const int k0 = it*64;
      if (it + 1 < nt){
        const int kn = (it+1)*64;
        u16* kdst = kb[(it+1)&1];
        u16* vdst = vb[(it+1)&1];
        #pragma unroll
        for (int i=0;i<2;i++){
          int slot = i*512 + tid;
          int kr = slot >> 4;
          int kc = ((slot & 15) << 4) ^ ((kr & 7) << 4);
          async16(Kb + (size_t)(kn + kr)*6144 + (kc >> 1), &kdst[(size_t)(i*512 + w*64)*8]);
          int vr = slot >> 3;
          int vc = ((slot & 7) << 4) ^ ((vr & 7) << 4);
          async16(Vb + (size_t)vr*2048 + kn + (vc >> 1), &vdst[(size_t)(i*512 + w*64)*8]);
        }
      }
      if (k0 <= qw + 15){
        const u16* kcur = kb[it&1];
        const u16* vcur = vb[it&1];
        f32x4 s[4];
        #pragma unroll
        for (int t=0;t<4;t++) s[t] = z;
        __builtin_amdgcn_s_setprio(1);
        #pragma unroll
        for (int t=0;t<4;t++){
          #pragma unroll
          for (int kd=0;kd<4;kd++){
            int row = t*16 + lo;
            int cb = (kd*64 + hi*16) ^ ((lo & 7) << 4);
            bf16x8 kk = *(const bf16x8*)&kcur[row*128 + (cb >> 1)];
            s[t] = __builtin_amdgcn_mfma_f32_16x16x32_bf16(qf[kd], kk, s[t], 0,0,0);
          }
        }
        __builtin_amdgcn_s_setprio(0);

        if (k0 + 63 > qw) {
          #pragma unroll
          for (int t=0;t<4;t++)
            #pragma unroll
            for (int r=0;r<4;r++){
              int q = qw + hi*4 + r;
              int k = k0 + t*16 + lo;
              if (k > q) s[t][r] = -3.0e38f;
            }
        }
        #pragma unroll
        for (int r=0;r<4;r++){
          float tm = fmaxf(fmaxf(s[0][r], s[1][r]), fmaxf(s[2][r], s[3][r]));
          tm = fmaxf(tm, __shfl_xor(tm, 1));
          tm = fmaxf(tm, __shfl_xor(tm, 2));
          tm = fmaxf(tm, __shfl_xor(tm, 4));
          tm = fmaxf(tm, __shfl_xor(tm, 8));
          tm *= sc;
          float mn = fmaxf(mx[r], tm);
          float al = exp2f(mx[r] - mn);
          mx[r] = mn;
          float p0 = exp2f(fmaf(s[0][r], sc, -mn));
          float p1 = exp2f(fmaf(s[1][r], sc, -mn));
          float p2 = exp2f(fmaf(s[2][r], sc, -mn));
          float p3 = exp2f(fmaf(s[3][r], sc, -mn));
          float sum = (p0 + p1) + (p2 + p3);
          sum += __shfl_xor(sum, 1);
          sum += __shfl_xor(sum, 2);
          sum += __shfl_xor(sum, 4);
          sum += __shfl_xor(sum, 8);
          lsum[r] = lsum[r]*al + sum;
          #pragma unroll
          for (int dj=0;dj<8;dj++) o[dj][r] *= al;
          int row = hi*4 + r;
          int sw = (row & 7) << 4;
          u16* prow = pw + row*64;
          prow[((     lo*2) ^ sw) >> 1] = f2bf(p0);
          prow[((32 + lo*2) ^ sw) >> 1] = f2bf(p1);
          prow[((64 + lo*2) ^ sw) >> 1] = f2bf(p2);
          prow[((96 + lo*2) ^ sw) >> 1] = f2bf(p3);
        }

        bf16x8 pa[2];
        #pragma unroll
        for (int kf=0;kf<2;kf++)
          pa[kf] = *(const bf16x8*)&pw[(lo*128 + ((kf*64 + hi*16) ^ ((lo & 7) << 4))) >> 1];
        __builtin_amdgcn_s_setprio(1);
        #pragma unroll
        for (int dj=0;dj<8;dj++){
          int row = dj*16 + lo;
          int cb0 = (hi*16)      ^ ((lo & 7) << 4);
          int cb1 = (64 + hi*16) ^ ((lo & 7) << 4);
          bf16x8 vv0 = *(const bf16x8*)&vcur[row*64 + (cb0 >> 1)];
          bf16x8 vv1 = *(const bf16x8*)&vcur[row*64 + (cb1 >> 1)];
          o[dj] = __builtin_amdgcn_mfma_f32_16x16x32_bf16(pa[0], vv0, o[dj], 0,0,0);
          o[dj] = __builtin_amdgcn_mfma_f32_16x16x32_bf16(pa[1], vv1, o[dj], 0,0,0);
        }
        __builtin_amdgcn_s_setprio(0);
      }
      __syncthreads();
    }

    #pragma unroll
    for (int r=0;r<4;r++){
      float inv = 1.0f / lsum[r];
      size_t row = (size_t)(b*2048 + qw + hi*4 + r);
      #pragma unroll
      for (int dj=0;dj<8;dj++)
        y[row*2048 + h*128 + dj*16 + lo] = f2bf(o[dj][r] * inv);
    }
    __syncthreads();
  }
}

extern "C" void kernel_launch(void* const* d_in, const int* in_sizes, int n_in,
                              void* d_out, int out_size, void* d_ws, size_t ws_size,
                              hipStream_t stream) {
  (void)in_sizes; (void)n_in; (void)out_size; (void)ws_size;
  const float* x      = (const float*)d_in[0];  // [8192][2048] f32
  const float* w_attn = (const float*)d_in[1];  // [2048][6144] f32
  const float* b_attn = (const float*)d_in[2];  // [6144] f32
  const float* w_proj = (const float*)d_in[3];  // [2048][2048] f32
  const float* b_proj = (const float*)d_in[4];  // [2048] f32
  float* out = (float*)d_out;                   // [8192][2048] f32

  char* ws = (char*)d_ws;
  u16* xbf = (u16*)(ws);                     // [8192][2048] bf16, 32 MB; reused as y
  u16* wT  = (u16*)(ws + 33554432);          // [6144][2048] bf16, 24 MB
  u16* pT  = (u16*)(ws + 58720256);          // [2048][2048] bf16,  8 MB
  u16* qkv = (u16*)(ws + 67108864);          // [8192][6144] bf16, 96 MB
  u16* vt  = (u16*)(ws + 167772160);         // [64][128][2048] bf16, 32 MB
  u16* y   = xbf;

  cvt_f2b<<<16384, 256, 0, stream>>>(x, xbf, 8192*2048);
  transpose2d_f2b<<<dim3(96,32), 256, 0, stream>>>(w_attn, wT, 2048, 6144);
  transpose2d_f2b<<<dim3(32,32), 256, 0, stream>>>(w_proj, pT, 2048, 2048);
  // QKV: M=8192 (64 m-tiles), N=6144 (24 n-tiles) -> 1536 blocks
  gemm_bt2<0><<<1536, 512, 0, stream>>>(xbf, wT, b_attn, qkv, 8192, 6144, 2048, 64);
  transpose_v<<<dim3(2,32,64), 256, 0, stream>>>(qkv, vt);
  attn_fwd<<<dim3(8,64), 512, 0, stream>>>(qkv, vt, y);
  // proj: M=8192 (64 m-tiles), N=2048 (8 n-tiles) -> 512 blocks
  gemm_bt2<1><<<512, 512, 0, stream>>>(y, pT, b_proj, out, 8192, 2048, 2048, 64);
}

// Round 8
// 529.976 us; speedup vs baseline: 2.4462x; 1.1388x over previous
//
#include <hip/hip_runtime.h>
#include <hip/hip_bf16.h>
#include <stdint.h>

typedef unsigned short u16;
typedef __bf16 bf16x8 __attribute__((ext_vector_type(8)));
typedef unsigned short u16x8 __attribute__((ext_vector_type(8)));
typedef float f32x4 __attribute__((ext_vector_type(4)));

__device__ __forceinline__ float bf2f(u16 u){ union{float f; unsigned i;} v; v.i = ((unsigned)u)<<16; return v.f; }
__device__ __forceinline__ u16 f2bf(float f){ union{float f; unsigned i;} v; v.f=f; unsigned r = v.i + 0x7FFFu + ((v.i>>16)&1u); return (u16)(r>>16); }

__device__ __forceinline__ void async16(const void* g, void* l){
  __builtin_amdgcn_global_load_lds((const __attribute__((address_space(1))) void*)g,
                                   (__attribute__((address_space(3))) void*)l, 16, 0, 0);
}

// ---------------- f32 -> bf16 elementwise cast ----------------
__global__ __launch_bounds__(256) void cvt_f2b(const float* __restrict__ src, u16* __restrict__ dst, int n)
{
  int i = (blockIdx.x * 256 + threadIdx.x) * 4;
  if (i < n) {
    float4 v = *(const float4*)&src[i];
    ushort4 o;
    o.x = f2bf(v.x); o.y = f2bf(v.y); o.z = f2bf(v.z); o.w = f2bf(v.w);
    *(ushort4*)&dst[i] = o;
  }
}

// ---------------- f32 src -> bf16 transposed dst, 64x64 tiles ----------------
__global__ __launch_bounds__(256) void transpose2d_f2b(const float* __restrict__ src, u16* __restrict__ dst,
                                                       int src_rows, int src_cols)
{
  __shared__ u16 tile[64][72];
  const int r0 = blockIdx.y << 6, c0 = blockIdx.x << 6;
  const int t = threadIdx.x;
  #pragma unroll
  for (int i=0;i<4;i++){
    int slot = t + (i<<8);
    int r = slot >> 4, cv = (slot & 15) << 2;
    float4 v = *(const float4*)&src[(size_t)(r0+r)*src_cols + c0 + cv];
    tile[r][cv+0] = f2bf(v.x); tile[r][cv+1] = f2bf(v.y);
    tile[r][cv+2] = f2bf(v.z); tile[r][cv+3] = f2bf(v.w);
  }
  __syncthreads();
  #pragma unroll
  for (int i=0;i<2;i++){
    int slot = t + (i<<8);
    int cr = slot >> 3, rv = (slot & 7) << 3;
    u16x8 v;
    #pragma unroll
    for (int e=0;e<8;e++) v[e] = tile[rv+e][cr];
    *(u16x8*)&dst[(size_t)(c0+cr)*src_rows + r0 + rv] = v;
  }
}

// ---------------- V transpose ----------------
__global__ __launch_bounds__(256) void transpose_v(const u16* __restrict__ qkv, u16* __restrict__ vt)
{
  __shared__ u16 tile[64][72];
  const int bh = blockIdx.z;
  const int b = bh >> 4, h = bh & 15;
  const u16* src = qkv + (size_t)b*2048*6144 + 4096 + h*128;
  u16* dst = vt + (size_t)bh*128*2048;
  const int t0 = blockIdx.y << 6, d0 = blockIdx.x << 6;
  const int t = threadIdx.x;
  #pragma unroll
  for (int i=0;i<2;i++){
    int slot = t + (i<<8);
    int r = slot >> 3, cv = (slot & 7) << 3;
    *(u16x8*)&tile[r][cv] = *(const u16x8*)&src[(size_t)(t0+r)*6144 + d0 + cv];
  }
  __syncthreads();
  #pragma unroll
  for (int i=0;i<2;i++){
    int slot = t + (i<<8);
    int cr = slot >> 3, rv = (slot & 7) << 3;
    u16x8 v;
    #pragma unroll
    for (int e=0;e<8;e++) v[e] = tile[rv+e][cr];
    *(u16x8*)&dst[(size_t)(d0+cr)*2048 + t0 + rv] = v;
  }
}

// ---------------- GEMM v3: 256x256 tile, 8-phase pipelined ----------------
// BM=BN=256, BK=64, 512 thr / 8 waves (2x4), wave out 128x64, acc[8][4].
// LDS [2 buf][2 khalf][256][32] planes for A and B (128 KB). Stage slot =
// A+B k-half planes (4 gloads/thr, lane-contiguous dest). Slots at phases
// 1,3,5,7; vmcnt(8) at even phases (2 slots in flight); region reuse freed
// exactly one phase before overwrite. Granule XOR (row&3) -> bank-optimal.
template<int F32OUT>
__global__ __launch_bounds__(512, 2) void gemm8p(const u16* __restrict__ A, const u16* __restrict__ Bt,
                                                 const float* __restrict__ bias, void* __restrict__ Cv,
                                                 int M, int N, int K, int mtiles)
{
  __shared__ u16 lsA[2][2][256*32];
  __shared__ u16 lsB[2][2][256*32];
  const int tid = threadIdx.x;
  const int w = tid >> 6, lane = tid & 63;
  const int wm = w >> 2, wn = w & 3;
  const int lo = lane & 15, hi = lane >> 4;

  const int nwg = gridDim.x;
  const int bid = blockIdx.x;
  const int swz = (bid & 7) * (nwg >> 3) + (bid >> 3);
  const int mt = swz % mtiles, nt = swz / mtiles;
  const int m0 = mt << 8, n0 = nt << 8;
  const int NT = K >> 6, NI = NT >> 1;

  const int s0 = tid, s1 = tid + 512;
  const size_t off0 = (size_t)(s0>>2)*K + (size_t)((((s0&3) ^ ((s0>>2)&3))) << 3);
  const size_t off1 = (size_t)(s1>>2)*K + (size_t)((((s1&3) ^ ((s1>>2)&3))) << 3);
  const u16* Asrc = A + (size_t)m0*K;
  const u16* Bsrc = Bt + (size_t)n0*K;

  f32x4 acc[8][4];
  f32x4 z = {0.f,0.f,0.f,0.f};
  #pragma unroll
  for (int i=0;i<8;i++)
    #pragma unroll
    for (int j=0;j<4;j++) acc[i][j] = z;

  bf16x8 bfr[4];

#define SLOT(T, KH, AP, BP) do { \
    const u16* as_ = Asrc + (T)*64 + (KH)*32; \
    const u16* bs_ = Bsrc + (T)*64 + (KH)*32; \
    async16(as_ + off0, &(AP)[s0*8]); \
    async16(as_ + off1, &(AP)[s1*8]); \
    async16(bs_ + off0, &(BP)[s0*8]); \
    async16(bs_ + off1, &(BP)[s1*8]); \
  } while(0)

#define LOADB(BUF, KS) do { \
    _Pragma("unroll") \
    for (int nf=0; nf<4; ++nf){ \
      int row_ = wn*64 + nf*16 + lo; \
      bfr[nf] = *(const bf16x8*)&lsB[BUF][KS][row_*32 + ((hi ^ (row_ & 3)) << 3)]; \
    } } while(0)

#define VM8 asm volatile("s_waitcnt vmcnt(8)" ::: "memory")
#define VM4 asm volatile("s_waitcnt vmcnt(4)" ::: "memory")
#define VM0 asm volatile("s_waitcnt vmcnt(0)" ::: "memory")
#define VMN do{}while(0)

#define PH(BUF, KS, Q, LB, WAIT, ...) do { \
    bf16x8 a_[4]; \
    _Pragma("unroll") \
    for (int mf=0; mf<4; ++mf){ \
      int row_ = wm*128 + Q*64 + mf*16 + lo; \
      a_[mf] = *(const bf16x8*)&lsA[BUF][KS][row_*32 + ((hi ^ (row_ & 3)) << 3)]; \
    } \
    if (LB) LOADB(BUF, KS); \
    __VA_ARGS__; \
    __builtin_amdgcn_s_barrier(); \
    __builtin_amdgcn_s_setprio(1); \
    _Pragma("unroll") \
    for (int mf=0; mf<4; ++mf) \
      _Pragma("unroll") \
      for (int nf=0; nf<4; ++nf) \
        acc[Q*4+mf][nf] = __builtin_amdgcn_mfma_f32_16x16x32_bf16(a_[mf], bfr[nf], acc[Q*4+mf][nf], 0,0,0); \
    __builtin_amdgcn_s_setprio(0); \
    WAIT; \
    __builtin_amdgcn_s_barrier(); \
    __builtin_amdgcn_sched_barrier(0); \
  } while(0)

  // prologue: stage (0,kh0), (0,kh1), (1,kh0)
  SLOT(0, 0, lsA[0][0], lsB[0][0]);
  SLOT(0, 1, lsA[0][1], lsB[0][1]);
  SLOT(1, 0, lsA[1][0], lsB[1][0]);
  VM8;
  __builtin_amdgcn_s_barrier();
  __builtin_amdgcn_sched_barrier(0);

  #pragma unroll 1
  for (int i = 0; i < NI-1; ++i){
    const int t0 = 2*i;
    PH(0,0,0, 1, VMN, SLOT(t0+1,1, lsA[1][1], lsB[1][1]));
    PH(0,0,1, 0, VM8, VMN);
    PH(0,1,0, 1, VMN, SLOT(t0+2,0, lsA[0][0], lsB[0][0]));
    PH(0,1,1, 0, VM8, VMN);
    PH(1,0,0, 1, VMN, SLOT(t0+2,1, lsA[0][1], lsB[0][1]));
    PH(1,0,1, 0, VM8, VMN);
    PH(1,1,0, 1, VMN, SLOT(t0+3,0, lsA[1][0], lsB[1][0]));
    PH(1,1,1, 0, VM8, VMN);
  }
  // final iteration (tiles NT-2, NT-1): only ph1's slot is in-range
  PH(0,0,0, 1, VMN, SLOT(NT-1,1, lsA[1][1], lsB[1][1]));
  PH(0,0,1, 0, VM8, VMN);
  PH(0,1,0, 1, VMN, VMN);
  PH(0,1,1, 0, VM4, VMN);
  PH(1,0,0, 1, VMN, VMN);
  PH(1,0,1, 0, VM0, VMN);
  PH(1,1,0, 1, VMN, VMN);
  PH(1,1,1, 0, VMN, VMN);

#undef PH
#undef SLOT
#undef LOADB

  float bv[4];
  #pragma unroll
  for (int nf=0;nf<4;nf++) bv[nf] = bias[n0 + wn*64 + nf*16 + lo];
  #pragma unroll
  for (int am=0;am<8;am++){
    int row = m0 + wm*128 + am*16 + hi*4;
    #pragma unroll
    for (int nf=0;nf<4;nf++){
      int col = n0 + wn*64 + nf*16 + lo;
      #pragma unroll
      for (int r=0;r<4;r++){
        float vv = acc[am][nf][r] + bv[nf];
        if (F32OUT) ((float*)Cv)[(size_t)(row+r)*N + col] = vv;
        else        ((u16*)Cv)[(size_t)(row+r)*N + col] = f2bf(vv);
      }
    }
  }
}

// ---------------- causal flash attention (v5, unchanged) ----------------
__global__ __launch_bounds__(512, 4) void attn_fwd(const u16* __restrict__ qkv, const u16* __restrict__ vt,
                                                   u16* __restrict__ y)
{
  __shared__ u16 kb[2][64*128];
  __shared__ u16 vb[2][128*64];
  __shared__ u16 plds[8][16*64];
  const int bh = blockIdx.y;
  const int b = bh >> 4, h = bh & 15;
  const int pair = blockIdx.x;
  const int tid = threadIdx.x;
  const int w = tid >> 6, lane = tid & 63;
  const int lo = lane & 15, hi = lane >> 4;

  const u16* Qb = qkv + (size_t)b*2048*6144 + h*128;
  const u16* Kb = Qb + 2048;
  const u16* Vb = vt + (size_t)bh*128*2048;
  u16* pw = &plds[w][0];
  const float sc = 0.08838834764831845f * 1.4426950408889634f;
  f32x4 z = {0.f,0.f,0.f,0.f};

  #pragma unroll 1
  for (int seg = 0; seg < 2; ++seg){
    const int qt = seg ? pair : 15 - pair;
    const int qw = qt*128 + w*16;
    const int nt = qt*2 + 2;

    bf16x8 qf[4];
    #pragma unroll
    for (int kd=0;kd<4;kd++)
      qf[kd] = *(const bf16x8*)&Qb[(size_t)(qw + lo)*6144 + kd*32 + hi*8];

    f32x4 o[8];
    #pragma unroll
    for (int dj=0;dj<8;dj++) o[dj] = z;
    float mx[4], lsum[4];
    #pragma unroll
    for (int r=0;r<4;r++){ mx[r] = -3.0e38f; lsum[r] = 0.f; }

    #pragma unroll
    for (int i=0;i<2;i++){
      int slot = i*512 + tid;
      int kr = slot >> 4;
      int kc = ((slot & 15) << 4) ^ ((kr & 7) << 4);
      async16(Kb + (size_t)kr*6144 + (kc >> 1), &kb[0][(size_t)(i*512 + w*64)*8]);
      int vr = slot >> 3;
      int vc = ((slot & 7) << 4) ^ ((vr & 7) << 4);
      async16(Vb + (size_t)vr*2048 + (vc >> 1), &vb[0][(size_t)(i*512 + w*64)*8]);
    }
    __syncthreads();

    #pragma unroll 1
    for (int it = 0; it < nt; ++it){
      const int k0 = it*64;
      if (it + 1 < nt){
        const int kn = (it+1)*64;
        u16* kdst = kb[(it+1)&1];
        u16* vdst = vb[(it+1)&1];
        #pragma unroll
        for (int i=0;i<2;i++){
          int slot = i*512 + tid;
          int kr = slot >> 4;
          int kc = ((slot & 15) << 4) ^ ((kr & 7) << 4);
          async16(Kb + (size_t)(kn + kr)*6144 + (kc >> 1), &kdst[(size_t)(i*512 + w*64)*8]);
          int vr = slot >> 3;
          int vc = ((slot & 7) << 4) ^ ((vr & 7) << 4);
          async16(Vb + (size_t)vr*2048 + kn + (vc >> 1), &vdst[(size_t)(i*512 + w*64)*8]);
        }
      }
      if (k0 <= qw + 15){
        const u16* kcur = kb[it&1];
        const u16* vcur = vb[it&1];
        f32x4 s[4];
        #pragma unroll
        for (int t=0;t<4;t++) s[t] = z;
        __builtin_amdgcn_s_setprio(1);
        #pragma unroll
        for (int t=0;t<4;t++){
          #pragma unroll
          for (int kd=0;kd<4;kd++){
            int row = t*16 + lo;
            int cb = (kd*64 + hi*16) ^ ((lo & 7) << 4);
            bf16x8 kk = *(const bf16x8*)&kcur[row*128 + (cb >> 1)];
            s[t] = __builtin_amdgcn_mfma_f32_16x16x32_bf16(qf[kd], kk, s[t], 0,0,0);
          }
        }
        __builtin_amdgcn_s_setprio(0);

        if (k0 + 63 > qw) {
          #pragma unroll
          for (int t=0;t<4;t++)
            #pragma unroll
            for (int r=0;r<4;r++){
              int q = qw + hi*4 + r;
              int k = k0 + t*16 + lo;
              if (k > q) s[t][r] = -3.0e38f;
            }
        }
        #pragma unroll
        for (int r=0;r<4;r++){
          float tm = fmaxf(fmaxf(s[0][r], s[1][r]), fmaxf(s[2][r], s[3][r]));
          tm = fmaxf(tm, __shfl_xor(tm, 1));
          tm = fmaxf(tm, __shfl_xor(tm, 2));
          tm = fmaxf(tm, __shfl_xor(tm, 4));
          tm = fmaxf(tm, __shfl_xor(tm, 8));
          tm *= sc;
          float mn = fmaxf(mx[r], tm);
          float al = exp2f(mx[r] - mn);
          mx[r] = mn;
          float p0 = exp2f(fmaf(s[0][r], sc, -mn));
          float p1 = exp2f(fmaf(s[1][r], sc, -mn));
          float p2 = exp2f(fmaf(s[2][r], sc, -mn));
          float p3 = exp2f(fmaf(s[3][r], sc, -mn));
          float sum = (p0 + p1) + (p2 + p3);
          sum += __shfl_xor(sum, 1);
          sum += __shfl_xor(sum, 2);
          sum += __shfl_xor(sum, 4);
          sum += __shfl_xor(sum, 8);
          lsum[r] = lsum[r]*al + sum;
          #pragma unroll
          for (int dj=0;dj<8;dj++) o[dj][r] *= al;
          int row = hi*4 + r;
          int sw = (row & 7) << 4;
          u16* prow = pw + row*64;
          prow[((     lo*2) ^ sw) >> 1] = f2bf(p0);
          prow[((32 + lo*2) ^ sw) >> 1] = f2bf(p1);
          prow[((64 + lo*2) ^ sw) >> 1] = f2bf(p2);
          prow[((96 + lo*2) ^ sw) >> 1] = f2bf(p3);
        }

        bf16x8 pa[2];
        #pragma unroll
        for (int kf=0;kf<2;kf++)
          pa[kf] = *(const bf16x8*)&pw[(lo*128 + ((kf*64 + hi*16) ^ ((lo & 7) << 4))) >> 1];
        __builtin_amdgcn_s_setprio(1);
        #pragma unroll
        for (int dj=0;dj<8;dj++){
          int row = dj*16 + lo;
          int cb0 = (hi*16)      ^ ((lo & 7) << 4);
          int cb1 = (64 + hi*16) ^ ((lo & 7) << 4);
          bf16x8 vv0 = *(const bf16x8*)&vcur[row*64 + (cb0 >> 1)];
          bf16x8 vv1 = *(const bf16x8*)&vcur[row*64 + (cb1 >> 1)];
          o[dj] = __builtin_amdgcn_mfma_f32_16x16x32_bf16(pa[0], vv0, o[dj], 0,0,0);
          o[dj] = __builtin_amdgcn_mfma_f32_16x16x32_bf16(pa[1], vv1, o[dj], 0,0,0);
        }
        __builtin_amdgcn_s_setprio(0);
      }
      __syncthreads();
    }

    #pragma unroll
    for (int r=0;r<4;r++){
      float inv = 1.0f / lsum[r];
      size_t row = (size_t)(b*2048 + qw + hi*4 + r);
      #pragma unroll
      for (int dj=0;dj<8;dj++)
        y[row*2048 + h*128 + dj*16 + lo] = f2bf(o[dj][r] * inv);
    }
    __syncthreads();
  }
}

extern "C" void kernel_launch(void* const* d_in, const int* in_sizes, int n_in,
                              void* d_out, int out_size, void* d_ws, size_t ws_size,
                              hipStream_t stream) {
  (void)in_sizes; (void)n_in; (void)out_size; (void)ws_size;
  const float* x      = (const float*)d_in[0];  // [8192][2048] f32
  const float* w_attn = (const float*)d_in[1];  // [2048][6144] f32
  const float* b_attn = (const float*)d_in[2];  // [6144] f32
  const float* w_proj = (const float*)d_in[3];  // [2048][2048] f32
  const float* b_proj = (const float*)d_in[4];  // [2048] f32
  float* out = (float*)d_out;                   // [8192][2048] f32

  char* ws = (char*)d_ws;
  u16* xbf = (u16*)(ws);                     // [8192][2048] bf16, 32 MB; reused as y
  u16* wT  = (u16*)(ws + 33554432);          // [6144][2048] bf16, 24 MB
  u16* pT  = (u16*)(ws + 58720256);          // [2048][2048] bf16,  8 MB
  u16* qkv = (u16*)(ws + 67108864);          // [8192][6144] bf16, 96 MB
  u16* vt  = (u16*)(ws + 167772160);         // [64][128][2048] bf16, 32 MB
  u16* y   = xbf;

  cvt_f2b<<<16384, 256, 0, stream>>>(x, xbf, 8192*2048);
  transpose2d_f2b<<<dim3(96,32), 256, 0, stream>>>(w_attn, wT, 2048, 6144);
  transpose2d_f2b<<<dim3(32,32), 256, 0, stream>>>(w_proj, pT, 2048, 2048);
  // QKV: 32 m-tiles x 24 n-tiles = 768 blocks
  gemm8p<0><<<768, 512, 0, stream>>>(xbf, wT, b_attn, qkv, 8192, 6144, 2048, 32);
  transpose_v<<<dim3(2,32,64), 256, 0, stream>>>(qkv, vt);
  attn_fwd<<<dim3(8,64), 512, 0, stream>>>(qkv, vt, y);
  // proj: 32 m-tiles x 8 n-tiles = 256 blocks
  gemm8p<1><<<256, 512, 0, stream>>>(y, pT, b_proj, out, 8192, 2048, 2048, 32);
}

// Round 9
// 527.100 us; speedup vs baseline: 2.4595x; 1.0055x over previous
//
#include <hip/hip_runtime.h>
#include <hip/hip_bf16.h>
#include <stdint.h>

typedef unsigned short u16;
typedef __bf16 bf16x8 __attribute__((ext_vector_type(8)));
typedef unsigned short u16x8 __attribute__((ext_vector_type(8)));
typedef float f32x4 __attribute__((ext_vector_type(4)));

__device__ __forceinline__ float bf2f(u16 u){ union{float f; unsigned i;} v; v.i = ((unsigned)u)<<16; return v.f; }
__device__ __forceinline__ u16 f2bf(float f){ union{float f; unsigned i;} v; v.f=f; unsigned r = v.i + 0x7FFFu + ((v.i>>16)&1u); return (u16)(r>>16); }

__device__ __forceinline__ void async16(const void* g, void* l){
  __builtin_amdgcn_global_load_lds((const __attribute__((address_space(1))) void*)g,
                                   (__attribute__((address_space(3))) void*)l, 16, 0, 0);
}

// ---------------- f32 -> bf16 elementwise cast ----------------
__global__ __launch_bounds__(256) void cvt_f2b(const float* __restrict__ src, u16* __restrict__ dst, int n)
{
  int i = (blockIdx.x * 256 + threadIdx.x) * 4;
  if (i < n) {
    float4 v = *(const float4*)&src[i];
    ushort4 o;
    o.x = f2bf(v.x); o.y = f2bf(v.y); o.z = f2bf(v.z); o.w = f2bf(v.w);
    *(ushort4*)&dst[i] = o;
  }
}

// ---------------- f32 src -> bf16 transposed dst, 64x64 tiles ----------------
__global__ __launch_bounds__(256) void transpose2d_f2b(const float* __restrict__ src, u16* __restrict__ dst,
                                                       int src_rows, int src_cols)
{
  __shared__ u16 tile[64][72];
  const int r0 = blockIdx.y << 6, c0 = blockIdx.x << 6;
  const int t = threadIdx.x;
  #pragma unroll
  for (int i=0;i<4;i++){
    int slot = t + (i<<8);
    int r = slot >> 4, cv = (slot & 15) << 2;
    float4 v = *(const float4*)&src[(size_t)(r0+r)*src_cols + c0 + cv];
    tile[r][cv+0] = f2bf(v.x); tile[r][cv+1] = f2bf(v.y);
    tile[r][cv+2] = f2bf(v.z); tile[r][cv+3] = f2bf(v.w);
  }
  __syncthreads();
  #pragma unroll
  for (int i=0;i<2;i++){
    int slot = t + (i<<8);
    int cr = slot >> 3, rv = (slot & 7) << 3;
    u16x8 v;
    #pragma unroll
    for (int e=0;e<8;e++) v[e] = tile[rv+e][cr];
    *(u16x8*)&dst[(size_t)(c0+cr)*src_rows + r0 + rv] = v;
  }
}

// ---------------- V transpose ----------------
__global__ __launch_bounds__(256) void transpose_v(const u16* __restrict__ qkv, u16* __restrict__ vt)
{
  __shared__ u16 tile[64][72];
  const int bh = blockIdx.z;
  const int b = bh >> 4, h = bh & 15;
  const u16* src = qkv + (size_t)b*2048*6144 + 4096 + h*128;
  u16* dst = vt + (size_t)bh*128*2048;
  const int t0 = blockIdx.y << 6, d0 = blockIdx.x << 6;
  const int t = threadIdx.x;
  #pragma unroll
  for (int i=0;i<2;i++){
    int slot = t + (i<<8);
    int r = slot >> 3, cv = (slot & 7) << 3;
    *(u16x8*)&tile[r][cv] = *(const u16x8*)&src[(size_t)(t0+r)*6144 + d0 + cv];
  }
  __syncthreads();
  #pragma unroll
  for (int i=0;i<2;i++){
    int slot = t + (i<<8);
    int cr = slot >> 3, rv = (slot & 7) << 3;
    u16x8 v;
    #pragma unroll
    for (int e=0;e<8;e++) v[e] = tile[rv+e][cr];
    *(u16x8*)&dst[(size_t)(d0+cr)*2048 + t0 + rv] = v;
  }
}

// ---------------- GEMM v3.1: 256x256 tile, 8-phase pipelined ----------------
// BM=BN=256, BK=64, 512 thr / 8 waves (2x4), wave out 128x64, acc[8][4].
// LDS [2 buf][2 khalf][256][32] planes (128 KB). Granule XOR (row>>1)&3:
// bank-slot (row&1)*4 + (hi^((row>>1)&3)) covers all 8 slots over 8 rows ->
// 2-way (free). Same involution on pre-swizzled global source and reads.
// vmcnt(8) steady state (2 slots in flight); schedule proven race-free (R8).
template<int F32OUT>
__global__ __launch_bounds__(512, 2) void gemm8p(const u16* __restrict__ A, const u16* __restrict__ Bt,
                                                 const float* __restrict__ bias, void* __restrict__ Cv,
                                                 int M, int N, int K, int mtiles)
{
  __shared__ u16 lsA[2][2][256*32];
  __shared__ u16 lsB[2][2][256*32];
  const int tid = threadIdx.x;
  const int w = tid >> 6, lane = tid & 63;
  const int wm = w >> 2, wn = w & 3;
  const int lo = lane & 15, hi = lane >> 4;

  const int nwg = gridDim.x;
  const int bid = blockIdx.x;
  const int swz = (bid & 7) * (nwg >> 3) + (bid >> 3);
  const int mt = swz % mtiles, nt = swz / mtiles;
  const int m0 = mt << 8, n0 = nt << 8;
  const int NT = K >> 6, NI = NT >> 1;

  const int s0 = tid, s1 = tid + 512;
  const size_t off0 = (size_t)(s0>>2)*K + (size_t)((((s0&3) ^ ((s0>>3)&3))) << 3);
  const size_t off1 = (size_t)(s1>>2)*K + (size_t)((((s1&3) ^ ((s1>>3)&3))) << 3);
  const u16* Asrc = A + (size_t)m0*K;
  const u16* Bsrc = Bt + (size_t)n0*K;

  f32x4 acc[8][4];
  f32x4 z = {0.f,0.f,0.f,0.f};
  #pragma unroll
  for (int i=0;i<8;i++)
    #pragma unroll
    for (int j=0;j<4;j++) acc[i][j] = z;

  bf16x8 bfr[4];

#define SLOT(T, KH, AP, BP) do { \
    const u16* as_ = Asrc + (T)*64 + (KH)*32; \
    const u16* bs_ = Bsrc + (T)*64 + (KH)*32; \
    async16(as_ + off0, &(AP)[s0*8]); \
    async16(as_ + off1, &(AP)[s1*8]); \
    async16(bs_ + off0, &(BP)[s0*8]); \
    async16(bs_ + off1, &(BP)[s1*8]); \
  } while(0)

#define LOADB(BUF, KS) do { \
    _Pragma("unroll") \
    for (int nf=0; nf<4; ++nf){ \
      int row_ = wn*64 + nf*16 + lo; \
      bfr[nf] = *(const bf16x8*)&lsB[BUF][KS][row_*32 + ((hi ^ ((row_>>1) & 3)) << 3)]; \
    } } while(0)

#define VM8 asm volatile("s_waitcnt vmcnt(8)" ::: "memory")
#define VM4 asm volatile("s_waitcnt vmcnt(4)" ::: "memory")
#define VM0 asm volatile("s_waitcnt vmcnt(0)" ::: "memory")
#define VMN do{}while(0)

#define PH(BUF, KS, Q, LB, WAIT, ...) do { \
    bf16x8 a_[4]; \
    _Pragma("unroll") \
    for (int mf=0; mf<4; ++mf){ \
      int row_ = wm*128 + Q*64 + mf*16 + lo; \
      a_[mf] = *(const bf16x8*)&lsA[BUF][KS][row_*32 + ((hi ^ ((row_>>1) & 3)) << 3)]; \
    } \
    if (LB) LOADB(BUF, KS); \
    __VA_ARGS__; \
    __builtin_amdgcn_s_barrier(); \
    __builtin_amdgcn_s_setprio(1); \
    _Pragma("unroll") \
    for (int mf=0; mf<4; ++mf) \
      _Pragma("unroll") \
      for (int nf=0; nf<4; ++nf) \
        acc[Q*4+mf][nf] = __builtin_amdgcn_mfma_f32_16x16x32_bf16(a_[mf], bfr[nf], acc[Q*4+mf][nf], 0,0,0); \
    __builtin_amdgcn_s_setprio(0); \
    WAIT; \
    __builtin_amdgcn_s_barrier(); \
    __builtin_amdgcn_sched_barrier(0); \
  } while(0)

  // prologue: stage (0,kh0), (0,kh1), (1,kh0)
  SLOT(0, 0, lsA[0][0], lsB[0][0]);
  SLOT(0, 1, lsA[0][1], lsB[0][1]);
  SLOT(1, 0, lsA[1][0], lsB[1][0]);
  VM8;
  __builtin_amdgcn_s_barrier();
  __builtin_amdgcn_sched_barrier(0);

  #pragma unroll 1
  for (int i = 0; i < NI-1; ++i){
    const int t0 = 2*i;
    PH(0,0,0, 1, VMN, SLOT(t0+1,1, lsA[1][1], lsB[1][1]));
    PH(0,0,1, 0, VM8, VMN);
    PH(0,1,0, 1, VMN, SLOT(t0+2,0, lsA[0][0], lsB[0][0]));
    PH(0,1,1, 0, VM8, VMN);
    PH(1,0,0, 1, VMN, SLOT(t0+2,1, lsA[0][1], lsB[0][1]));
    PH(1,0,1, 0, VM8, VMN);
    PH(1,1,0, 1, VMN, SLOT(t0+3,0, lsA[1][0], lsB[1][0]));
    PH(1,1,1, 0, VM8, VMN);
  }
  // final iteration (tiles NT-2, NT-1)
  PH(0,0,0, 1, VMN, SLOT(NT-1,1, lsA[1][1], lsB[1][1]));
  PH(0,0,1, 0, VM8, VMN);
  PH(0,1,0, 1, VMN, VMN);
  PH(0,1,1, 0, VM4, VMN);
  PH(1,0,0, 1, VMN, VMN);
  PH(1,0,1, 0, VM0, VMN);
  PH(1,1,0, 1, VMN, VMN);
  PH(1,1,1, 0, VMN, VMN);

#undef PH
#undef SLOT
#undef LOADB

  float bv[4];
  #pragma unroll
  for (int nf=0;nf<4;nf++) bv[nf] = bias[n0 + wn*64 + nf*16 + lo];
  #pragma unroll
  for (int am=0;am<8;am++){
    int row = m0 + wm*128 + am*16 + hi*4;
    #pragma unroll
    for (int nf=0;nf<4;nf++){
      int col = n0 + wn*64 + nf*16 + lo;
      #pragma unroll
      for (int r=0;r<4;r++){
        float vv = acc[am][nf][r] + bv[nf];
        if (F32OUT) ((float*)Cv)[(size_t)(row+r)*N + col] = vv;
        else        ((u16*)Cv)[(size_t)(row+r)*N + col] = f2bf(vv);
      }
    }
  }
}

// ---------------- causal flash attention (v5, unchanged) ----------------
__global__ __launch_bounds__(512, 4) void attn_fwd(const u16* __restrict__ qkv, const u16* __restrict__ vt,
                                                   u16* __restrict__ y)
{
  __shared__ u16 kb[2][64*128];
  __shared__ u16 vb[2][128*64];
  __shared__ u16 plds[8][16*64];
  const int bh = blockIdx.y;
  const int b = bh >> 4, h = bh & 15;
  const int pair = blockIdx.x;
  const int tid = threadIdx.x;
  const int w = tid >> 6, lane = tid & 63;
  const int lo = lane & 15, hi = lane >> 4;

  const u16* Qb = qkv + (size_t)b*2048*6144 + h*128;
  const u16* Kb = Qb + 2048;
  const u16* Vb = vt + (size_t)bh*128*2048;
  u16* pw = &plds[w][0];
  const float sc = 0.08838834764831845f * 1.4426950408889634f;
  f32x4 z = {0.f,0.f,0.f,0.f};

  #pragma unroll 1
  for (int seg = 0; seg < 2; ++seg){
    const int qt = seg ? pair : 15 - pair;
    const int qw = qt*128 + w*16;
    const int nt = qt*2 + 2;

    bf16x8 qf[4];
    #pragma unroll
    for (int kd=0;kd<4;kd++)
      qf[kd] = *(const bf16x8*)&Qb[(size_t)(qw + lo)*6144 + kd*32 + hi*8];

    f32x4 o[8];
    #pragma unroll
    for (int dj=0;dj<8;dj++) o[dj] = z;
    float mx[4], lsum[4];
    #pragma unroll
    for (int r=0;r<4;r++){ mx[r] = -3.0e38f; lsum[r] = 0.f; }

    #pragma unroll
    for (int i=0;i<2;i++){
      int slot = i*512 + tid;
      int kr = slot >> 4;
      int kc = ((slot & 15) << 4) ^ ((kr & 7) << 4);
      async16(Kb + (size_t)kr*6144 + (kc >> 1), &kb[0][(size_t)(i*512 + w*64)*8]);
      int vr = slot >> 3;
      int vc = ((slot & 7) << 4) ^ ((vr & 7) << 4);
      async16(Vb + (size_t)vr*2048 + (vc >> 1), &vb[0][(size_t)(i*512 + w*64)*8]);
    }
    __syncthreads();

    #pragma unroll 1
    for (int it = 0; it < nt; ++it){
      const int k0 = it*64;
      if (it + 1 < nt){
        const int kn = (it+1)*64;
        u16* kdst = kb[(it+1)&1];
        u16* vdst = vb[(it+1)&1];
        #pragma unroll
        for (int i=0;i<2;i++){
          int slot = i*512 + tid;
          int kr = slot >> 4;
          int kc = ((slot & 15) << 4) ^ ((kr & 7) << 4);
          async16(Kb + (size_t)(kn + kr)*6144 + (kc >> 1), &kdst[(size_t)(i*512 + w*64)*8]);
          int vr = slot >> 3;
          int vc = ((slot & 7) << 4) ^ ((vr & 7) << 4);
          async16(Vb + (size_t)vr*2048 + kn + (vc >> 1), &vdst[(size_t)(i*512 + w*64)*8]);
        }
      }
      if (k0 <= qw + 15){
        const u16* kcur = kb[it&1];
        const u16* vcur = vb[it&1];
        f32x4 s[4];
        #pragma unroll
        for (int t=0;t<4;t++) s[t] = z;
        __builtin_amdgcn_s_setprio(1);
        #pragma unroll
        for (int t=0;t<4;t++){
          #pragma unroll
          for (int kd=0;kd<4;kd++){
            int row = t*16 + lo;
            int cb = (kd*64 + hi*16) ^ ((lo & 7) << 4);
            bf16x8 kk = *(const bf16x8*)&kcur[row*128 + (cb >> 1)];
            s[t] = __builtin_amdgcn_mfma_f32_16x16x32_bf16(qf[kd], kk, s[t], 0,0,0);
          }
        }
        __builtin_amdgcn_s_setprio(0);

        if (k0 + 63 > qw) {
          #pragma unroll
          for (int t=0;t<4;t++)
            #pragma unroll
            for (int r=0;r<4;r++){
              int q = qw + hi*4 + r;
              int k = k0 + t*16 + lo;
              if (k > q) s[t][r] = -3.0e38f;
            }
        }
        #pragma unroll
        for (int r=0;r<4;r++){
          float tm = fmaxf(fmaxf(s[0][r], s[1][r]), fmaxf(s[2][r], s[3][r]));
          tm = fmaxf(tm, __shfl_xor(tm, 1));
          tm = fmaxf(tm, __shfl_xor(tm, 2));
          tm = fmaxf(tm, __shfl_xor(tm, 4));
          tm = fmaxf(tm, __shfl_xor(tm, 8));
          tm *= sc;
          float mn = fmaxf(mx[r], tm);
          float al = exp2f(mx[r] - mn);
          mx[r] = mn;
          float p0 = exp2f(fmaf(s[0][r], sc, -mn));
          float p1 = exp2f(fmaf(s[1][r], sc, -mn));
          float p2 = exp2f(fmaf(s[2][r], sc, -mn));
          float p3 = exp2f(fmaf(s[3][r], sc, -mn));
          float sum = (p0 + p1) + (p2 + p3);
          sum += __shfl_xor(sum, 1);
          sum += __shfl_xor(sum, 2);
          sum += __shfl_xor(sum, 4);
          sum += __shfl_xor(sum, 8);
          lsum[r] = lsum[r]*al + sum;
          #pragma unroll
          for (int dj=0;dj<8;dj++) o[dj][r] *= al;
          int row = hi*4 + r;
          int sw = (row & 7) << 4;
          u16* prow = pw + row*64;
          prow[((     lo*2) ^ sw) >> 1] = f2bf(p0);
          prow[((32 + lo*2) ^ sw) >> 1] = f2bf(p1);
          prow[((64 + lo*2) ^ sw) >> 1] = f2bf(p2);
          prow[((96 + lo*2) ^ sw) >> 1] = f2bf(p3);
        }

        bf16x8 pa[2];
        #pragma unroll
        for (int kf=0;kf<2;kf++)
          pa[kf] = *(const bf16x8*)&pw[(lo*128 + ((kf*64 + hi*16) ^ ((lo & 7) << 4))) >> 1];
        __builtin_amdgcn_s_setprio(1);
        #pragma unroll
        for (int dj=0;dj<8;dj++){
          int row = dj*16 + lo;
          int cb0 = (hi*16)      ^ ((lo & 7) << 4);
          int cb1 = (64 + hi*16) ^ ((lo & 7) << 4);
          bf16x8 vv0 = *(const bf16x8*)&vcur[row*64 + (cb0 >> 1)];
          bf16x8 vv1 = *(const bf16x8*)&vcur[row*64 + (cb1 >> 1)];
          o[dj] = __builtin_amdgcn_mfma_f32_16x16x32_bf16(pa[0], vv0, o[dj], 0,0,0);
          o[dj] = __builtin_amdgcn_mfma_f32_16x16x32_bf16(pa[1], vv1, o[dj], 0,0,0);
        }
        __builtin_amdgcn_s_setprio(0);
      }
      __syncthreads();
    }

    #pragma unroll
    for (int r=0;r<4;r++){
      float inv = 1.0f / lsum[r];
      size_t row = (size_t)(b*2048 + qw + hi*4 + r);
      #pragma unroll
      for (int dj=0;dj<8;dj++)
        y[row*2048 + h*128 + dj*16 + lo] = f2bf(o[dj][r] * inv);
    }
    __syncthreads();
  }
}

extern "C" void kernel_launch(void* const* d_in, const int* in_sizes, int n_in,
                              void* d_out, int out_size, void* d_ws, size_t ws_size,
                              hipStream_t stream) {
  (void)in_sizes; (void)n_in; (void)out_size; (void)ws_size;
  const float* x      = (const float*)d_in[0];  // [8192][2048] f32
  const float* w_attn = (const float*)d_in[1];  // [2048][6144] f32
  const float* b_attn = (const float*)d_in[2];  // [6144] f32
  const float* w_proj = (const float*)d_in[3];  // [2048][2048] f32
  const float* b_proj = (const float*)d_in[4];  // [2048] f32
  float* out = (float*)d_out;                   // [8192][2048] f32

  char* ws = (char*)d_ws;
  u16* xbf = (u16*)(ws);                     // [8192][2048] bf16, 32 MB; reused as y
  u16* wT  = (u16*)(ws + 33554432);          // [6144][2048] bf16, 24 MB
  u16* pT  = (u16*)(ws + 58720256);          // [2048][2048] bf16,  8 MB
  u16* qkv = (u16*)(ws + 67108864);          // [8192][6144] bf16, 96 MB
  u16* vt  = (u16*)(ws + 167772160);         // [64][128][2048] bf16, 32 MB
  u16* y   = xbf;

  cvt_f2b<<<16384, 256, 0, stream>>>(x, xbf, 8192*2048);
  transpose2d_f2b<<<dim3(96,32), 256, 0, stream>>>(w_attn, wT, 2048, 6144);
  transpose2d_f2b<<<dim3(32,32), 256, 0, stream>>>(w_proj, pT, 2048, 2048);
  // QKV: 32 m-tiles x 24 n-tiles = 768 blocks
  gemm8p<0><<<768, 512, 0, stream>>>(xbf, wT, b_attn, qkv, 8192, 6144, 2048, 32);
  transpose_v<<<dim3(2,32,64), 256, 0, stream>>>(qkv, vt);
  attn_fwd<<<dim3(8,64), 512, 0, stream>>>(qkv, vt, y);
  // proj: 32 m-tiles x 8 n-tiles = 256 blocks
  gemm8p<1><<<256, 512, 0, stream>>>(y, pT, b_proj, out, 8192, 2048, 2048, 32);
}

// Round 10
// 506.910 us; speedup vs baseline: 2.5575x; 1.0398x over previous
//
#include <hip/hip_runtime.h>
#include <hip/hip_bf16.h>
#include <stdint.h>

typedef unsigned short u16;
typedef __bf16 bf16x8 __attribute__((ext_vector_type(8)));
typedef unsigned short u16x8 __attribute__((ext_vector_type(8)));
typedef float f32x4 __attribute__((ext_vector_type(4)));

__device__ __forceinline__ float bf2f(u16 u){ union{float f; unsigned i;} v; v.i = ((unsigned)u)<<16; return v.f; }
__device__ __forceinline__ u16 f2bf(float f){ union{float f; unsigned i;} v; v.f=f; unsigned r = v.i + 0x7FFFu + ((v.i>>16)&1u); return (u16)(r>>16); }

__device__ __forceinline__ void async16(const void* g, void* l){
  __builtin_amdgcn_global_load_lds((const __attribute__((address_space(1))) void*)g,
                                   (__attribute__((address_space(3))) void*)l, 16, 0, 0);
}

// ---------------- f32 -> bf16 elementwise cast ----------------
__global__ __launch_bounds__(256) void cvt_f2b(const float* __restrict__ src, u16* __restrict__ dst, int n)
{
  int i = (blockIdx.x * 256 + threadIdx.x) * 4;
  if (i < n) {
    float4 v = *(const float4*)&src[i];
    ushort4 o;
    o.x = f2bf(v.x); o.y = f2bf(v.y); o.z = f2bf(v.z); o.w = f2bf(v.w);
    *(ushort4*)&dst[i] = o;
  }
}

// ---------------- f32 src -> bf16 transposed dst, 64x64 tiles ----------------
__global__ __launch_bounds__(256) void transpose2d_f2b(const float* __restrict__ src, u16* __restrict__ dst,
                                                       int src_rows, int src_cols)
{
  __shared__ u16 tile[64][72];
  const int r0 = blockIdx.y << 6, c0 = blockIdx.x << 6;
  const int t = threadIdx.x;
  #pragma unroll
  for (int i=0;i<4;i++){
    int slot = t + (i<<8);
    int r = slot >> 4, cv = (slot & 15) << 2;
    float4 v = *(const float4*)&src[(size_t)(r0+r)*src_cols + c0 + cv];
    tile[r][cv+0] = f2bf(v.x); tile[r][cv+1] = f2bf(v.y);
    tile[r][cv+2] = f2bf(v.z); tile[r][cv+3] = f2bf(v.w);
  }
  __syncthreads();
  #pragma unroll
  for (int i=0;i<2;i++){
    int slot = t + (i<<8);
    int cr = slot >> 3, rv = (slot & 7) << 3;
    u16x8 v;
    #pragma unroll
    for (int e=0;e<8;e++) v[e] = tile[rv+e][cr];
    *(u16x8*)&dst[(size_t)(c0+cr)*src_rows + r0 + rv] = v;
  }
}

// ---------------- V transpose ----------------
__global__ __launch_bounds__(256) void transpose_v(const u16* __restrict__ qkv, u16* __restrict__ vt)
{
  __shared__ u16 tile[64][72];
  const int bh = blockIdx.z;
  const int b = bh >> 4, h = bh & 15;
  const u16* src = qkv + (size_t)b*2048*6144 + 4096 + h*128;
  u16* dst = vt + (size_t)bh*128*2048;
  const int t0 = blockIdx.y << 6, d0 = blockIdx.x << 6;
  const int t = threadIdx.x;
  #pragma unroll
  for (int i=0;i<2;i++){
    int slot = t + (i<<8);
    int r = slot >> 3, cv = (slot & 7) << 3;
    *(u16x8*)&tile[r][cv] = *(const u16x8*)&src[(size_t)(t0+r)*6144 + d0 + cv];
  }
  __syncthreads();
  #pragma unroll
  for (int i=0;i<2;i++){
    int slot = t + (i<<8);
    int cr = slot >> 3, rv = (slot & 7) << 3;
    u16x8 v;
    #pragma unroll
    for (int e=0;e<8;e++) v[e] = tile[rv+e][cr];
    *(u16x8*)&dst[(size_t)(d0+cr)*2048 + t0 + rv] = v;
  }
}

// ---------------- GEMM v4: 256x256, 8-phase, register-double-buffered ----------------
// Phase p prefetches phase p+1's fragments (alt reg set), waits counted
// lgkmcnt(own issues) so prev-phase frags are ready, MFMAs on prev set while
// LDS services the prefetch. One barrier/phase; VM8 end of odd phases.
// Hazards: stage->first-read gap = 5 phases for every plane; VM8+barrier
// publishes each plane exactly one phase before its first read.
template<int F32OUT>
__global__ __launch_bounds__(512, 2) void gemm8p(const u16* __restrict__ A, const u16* __restrict__ Bt,
                                                 const float* __restrict__ bias, void* __restrict__ Cv,
                                                 int M, int N, int K, int mtiles)
{
  __shared__ u16 lsA[2][2][256*32];
  __shared__ u16 lsB[2][2][256*32];
  const int tid = threadIdx.x;
  const int w = tid >> 6, lane = tid & 63;
  const int wm = w >> 2, wn = w & 3;
  const int lo = lane & 15, hi = lane >> 4;

  const int nwg = gridDim.x;
  const int bid = blockIdx.x;
  const int swz = (bid & 7) * (nwg >> 3) + (bid >> 3);
  const int mt = swz % mtiles, nt = swz / mtiles;
  const int m0 = mt << 8, n0 = nt << 8;
  const int NT = K >> 6, NI = NT >> 1;

  const int s0 = tid, s1 = tid + 512;
  const size_t off0 = (size_t)(s0>>2)*K + (size_t)((((s0&3) ^ ((s0>>3)&3))) << 3);
  const size_t off1 = (size_t)(s1>>2)*K + (size_t)((((s1&3) ^ ((s1>>3)&3))) << 3);
  const u16* Asrc = A + (size_t)m0*K;
  const u16* Bsrc = Bt + (size_t)n0*K;

  f32x4 acc[8][4];
  f32x4 z = {0.f,0.f,0.f,0.f};
  #pragma unroll
  for (int i=0;i<8;i++)
    #pragma unroll
    for (int j=0;j<4;j++) acc[i][j] = z;

  bf16x8 aE[4], aO[4], bX[4], bY[4];

#define SLOT(T, KH, AP, BP) do { \
    const u16* as_ = Asrc + (T)*64 + (KH)*32; \
    const u16* bs_ = Bsrc + (T)*64 + (KH)*32; \
    async16(as_ + off0, &(AP)[s0*8]); \
    async16(as_ + off1, &(AP)[s1*8]); \
    async16(bs_ + off0, &(BP)[s0*8]); \
    async16(bs_ + off1, &(BP)[s1*8]); \
  } while(0)

#define RDA(SET, BUF, KS, Q) do { \
    _Pragma("unroll") \
    for (int mf=0; mf<4; ++mf){ \
      int row_ = wm*128 + (Q)*64 + mf*16 + lo; \
      SET[mf] = *(const bf16x8*)&lsA[BUF][KS][row_*32 + ((hi ^ ((row_>>1) & 3)) << 3)]; \
    } } while(0)

#define RDB(SET, BUF, KS) do { \
    _Pragma("unroll") \
    for (int nf=0; nf<4; ++nf){ \
      int row_ = wn*64 + nf*16 + lo; \
      SET[nf] = *(const bf16x8*)&lsB[BUF][KS][row_*32 + ((hi ^ ((row_>>1) & 3)) << 3)]; \
    } } while(0)

#define MM(Q, AS, BS) do { \
    __builtin_amdgcn_s_setprio(1); \
    _Pragma("unroll") \
    for (int mf=0; mf<4; ++mf) \
      _Pragma("unroll") \
      for (int nf=0; nf<4; ++nf) \
        acc[(Q)*4+mf][nf] = __builtin_amdgcn_mfma_f32_16x16x32_bf16(AS[mf], BS[nf], acc[(Q)*4+mf][nf], 0,0,0); \
    __builtin_amdgcn_s_setprio(0); \
  } while(0)

#define LGK4 do { asm volatile("s_waitcnt lgkmcnt(4)" ::: "memory"); __builtin_amdgcn_sched_barrier(0); } while(0)
#define LGK8 do { asm volatile("s_waitcnt lgkmcnt(8)" ::: "memory"); __builtin_amdgcn_sched_barrier(0); } while(0)
#define LGK0 do { asm volatile("s_waitcnt lgkmcnt(0)" ::: "memory"); __builtin_amdgcn_sched_barrier(0); } while(0)
#define VM8 asm volatile("s_waitcnt vmcnt(8)" ::: "memory")
#define VM4 asm volatile("s_waitcnt vmcnt(4)" ::: "memory")
#define VM0 asm volatile("s_waitcnt vmcnt(0)" ::: "memory")
#define ENDP do { __builtin_amdgcn_s_barrier(); __builtin_amdgcn_sched_barrier(0); } while(0)

  // prologue: stage (0,kh0),(0,kh1),(1,kh0); publish (0,kh0); prefetch p1 frags
  SLOT(0, 0, lsA[0][0], lsB[0][0]);
  SLOT(0, 1, lsA[0][1], lsB[0][1]);
  SLOT(1, 0, lsA[1][0], lsB[1][0]);
  VM8;
  __builtin_amdgcn_s_barrier();
  __builtin_amdgcn_sched_barrier(0);
  RDA(aO, 0,0, 0); RDB(bX, 0,0);

  #pragma unroll 1
  for (int i = 0; i < NI-1; ++i){
    const int t0 = 2*i;
    RDA(aE, 0,0, 1); SLOT(t0+1,1, lsA[1][1], lsB[1][1]); LGK4; MM(0, aO, bX); VM8; ENDP;   // p1
    RDA(aO, 0,1, 0); RDB(bY, 0,1);                       LGK8; MM(1, aE, bX);      ENDP;   // p2
    RDA(aE, 0,1, 1); SLOT(t0+2,0, lsA[0][0], lsB[0][0]); LGK4; MM(0, aO, bY); VM8; ENDP;   // p3
    RDA(aO, 1,0, 0); RDB(bX, 1,0);                       LGK8; MM(1, aE, bY);      ENDP;   // p4
    RDA(aE, 1,0, 1); SLOT(t0+2,1, lsA[0][1], lsB[0][1]); LGK4; MM(0, aO, bX); VM8; ENDP;   // p5
    RDA(aO, 1,1, 0); RDB(bY, 1,1);                       LGK8; MM(1, aE, bX);      ENDP;   // p6
    RDA(aE, 1,1, 1); SLOT(t0+3,0, lsA[1][0], lsB[1][0]); LGK4; MM(0, aO, bY); VM8; ENDP;   // p7
    RDA(aO, 0,0, 0); RDB(bX, 0,0);                       LGK8; MM(1, aE, bY);      ENDP;   // p8 (tile t0+2)
  }
  // final iteration: tiles NT-2, NT-1
  RDA(aE, 0,0, 1); SLOT(NT-1,1, lsA[1][1], lsB[1][1]);   LGK4; MM(0, aO, bX); VM8; ENDP;   // p1
  RDA(aO, 0,1, 0); RDB(bY, 0,1);                         LGK8; MM(1, aE, bX);      ENDP;   // p2
  RDA(aE, 0,1, 1);                                       LGK4; MM(0, aO, bY); VM4; ENDP;   // p3
  RDA(aO, 1,0, 0); RDB(bX, 1,0);                         LGK8; MM(1, aE, bY);      ENDP;   // p4
  RDA(aE, 1,0, 1);                                       LGK4; MM(0, aO, bX); VM0; ENDP;   // p5
  RDA(aO, 1,1, 0); RDB(bY, 1,1);                         LGK8; MM(1, aE, bX);      ENDP;   // p6
  RDA(aE, 1,1, 1);                                       LGK4; MM(0, aO, bY);      ENDP;   // p7
                                                         LGK0; MM(1, aE, bY);             // p8

#undef SLOT
#undef RDA
#undef RDB
#undef MM

  float bv[4];
  #pragma unroll
  for (int nf=0;nf<4;nf++) bv[nf] = bias[n0 + wn*64 + nf*16 + lo];
  #pragma unroll
  for (int am=0;am<8;am++){
    int row = m0 + wm*128 + am*16 + hi*4;
    #pragma unroll
    for (int nf=0;nf<4;nf++){
      int col = n0 + wn*64 + nf*16 + lo;
      #pragma unroll
      for (int r=0;r<4;r++){
        float vv = acc[am][nf][r] + bv[nf];
        if (F32OUT) ((float*)Cv)[(size_t)(row+r)*N + col] = vv;
        else        ((u16*)Cv)[(size_t)(row+r)*N + col] = f2bf(vv);
      }
    }
  }
}

// ---------------- causal flash attention (v5, unchanged) ----------------
__global__ __launch_bounds__(512, 4) void attn_fwd(const u16* __restrict__ qkv, const u16* __restrict__ vt,
                                                   u16* __restrict__ y)
{
  __shared__ u16 kb[2][64*128];
  __shared__ u16 vb[2][128*64];
  __shared__ u16 plds[8][16*64];
  const int bh = blockIdx.y;
  const int b = bh >> 4, h = bh & 15;
  const int pair = blockIdx.x;
  const int tid = threadIdx.x;
  const int w = tid >> 6, lane = tid & 63;
  const int lo = lane & 15, hi = lane >> 4;

  const u16* Qb = qkv + (size_t)b*2048*6144 + h*128;
  const u16* Kb = Qb + 2048;
  const u16* Vb = vt + (size_t)bh*128*2048;
  u16* pw = &plds[w][0];
  const float sc = 0.08838834764831845f * 1.4426950408889634f;
  f32x4 z = {0.f,0.f,0.f,0.f};

  #pragma unroll 1
  for (int seg = 0; seg < 2; ++seg){
    const int qt = seg ? pair : 15 - pair;
    const int qw = qt*128 + w*16;
    const int nt = qt*2 + 2;

    bf16x8 qf[4];
    #pragma unroll
    for (int kd=0;kd<4;kd++)
      qf[kd] = *(const bf16x8*)&Qb[(size_t)(qw + lo)*6144 + kd*32 + hi*8];

    f32x4 o[8];
    #pragma unroll
    for (int dj=0;dj<8;dj++) o[dj] = z;
    float mx[4], lsum[4];
    #pragma unroll
    for (int r=0;r<4;r++){ mx[r] = -3.0e38f; lsum[r] = 0.f; }

    #pragma unroll
    for (int i=0;i<2;i++){
      int slot = i*512 + tid;
      int kr = slot >> 4;
      int kc = ((slot & 15) << 4) ^ ((kr & 7) << 4);
      async16(Kb + (size_t)kr*6144 + (kc >> 1), &kb[0][(size_t)(i*512 + w*64)*8]);
      int vr = slot >> 3;
      int vc = ((slot & 7) << 4) ^ ((vr & 7) << 4);
      async16(Vb + (size_t)vr*2048 + (vc >> 1), &vb[0][(size_t)(i*512 + w*64)*8]);
    }
    __syncthreads();

    #pragma unroll 1
    for (int it = 0; it < nt; ++it){
      const int k0 = it*64;
      if (it + 1 < nt){
        const int kn = (it+1)*64;
        u16* kdst = kb[(it+1)&1];
        u16* vdst = vb[(it+1)&1];
        #pragma unroll
        for (int i=0;i<2;i++){
          int slot = i*512 + tid;
          int kr = slot >> 4;
          int kc = ((slot & 15) << 4) ^ ((kr & 7) << 4);
          async16(Kb + (size_t)(kn + kr)*6144 + (kc >> 1), &kdst[(size_t)(i*512 + w*64)*8]);
          int vr = slot >> 3;
          int vc = ((slot & 7) << 4) ^ ((vr & 7) << 4);
          async16(Vb + (size_t)vr*2048 + kn + (vc >> 1), &vdst[(size_t)(i*512 + w*64)*8]);
        }
      }
      if (k0 <= qw + 15){
        const u16* kcur = kb[it&1];
        const u16* vcur = vb[it&1];
        f32x4 s[4];
        #pragma unroll
        for (int t=0;t<4;t++) s[t] = z;
        __builtin_amdgcn_s_setprio(1);
        #pragma unroll
        for (int t=0;t<4;t++){
          #pragma unroll
          for (int kd=0;kd<4;kd++){
            int row = t*16 + lo;
            int cb = (kd*64 + hi*16) ^ ((lo & 7) << 4);
            bf16x8 kk = *(const bf16x8*)&kcur[row*128 + (cb >> 1)];
            s[t] = __builtin_amdgcn_mfma_f32_16x16x32_bf16(qf[kd], kk, s[t], 0,0,0);
          }
        }
        __builtin_amdgcn_s_setprio(0);

        if (k0 + 63 > qw) {
          #pragma unroll
          for (int t=0;t<4;t++)
            #pragma unroll
            for (int r=0;r<4;r++){
              int q = qw + hi*4 + r;
              int k = k0 + t*16 + lo;
              if (k > q) s[t][r] = -3.0e38f;
            }
        }
        #pragma unroll
        for (int r=0;r<4;r++){
          float tm = fmaxf(fmaxf(s[0][r], s[1][r]), fmaxf(s[2][r], s[3][r]));
          tm = fmaxf(tm, __shfl_xor(tm, 1));
          tm = fmaxf(tm, __shfl_xor(tm, 2));
          tm = fmaxf(tm, __shfl_xor(tm, 4));
          tm = fmaxf(tm, __shfl_xor(tm, 8));
          tm *= sc;
          float mn = fmaxf(mx[r], tm);
          float al = exp2f(mx[r] - mn);
          mx[r] = mn;
          float p0 = exp2f(fmaf(s[0][r], sc, -mn));
          float p1 = exp2f(fmaf(s[1][r], sc, -mn));
          float p2 = exp2f(fmaf(s[2][r], sc, -mn));
          float p3 = exp2f(fmaf(s[3][r], sc, -mn));
          float sum = (p0 + p1) + (p2 + p3);
          sum += __shfl_xor(sum, 1);
          sum += __shfl_xor(sum, 2);
          sum += __shfl_xor(sum, 4);
          sum += __shfl_xor(sum, 8);
          lsum[r] = lsum[r]*al + sum;
          #pragma unroll
          for (int dj=0;dj<8;dj++) o[dj][r] *= al;
          int row = hi*4 + r;
          int sw = (row & 7) << 4;
          u16* prow = pw + row*64;
          prow[((     lo*2) ^ sw) >> 1] = f2bf(p0);
          prow[((32 + lo*2) ^ sw) >> 1] = f2bf(p1);
          prow[((64 + lo*2) ^ sw) >> 1] = f2bf(p2);
          prow[((96 + lo*2) ^ sw) >> 1] = f2bf(p3);
        }

        bf16x8 pa[2];
        #pragma unroll
        for (int kf=0;kf<2;kf++)
          pa[kf] = *(const bf16x8*)&pw[(lo*128 + ((kf*64 + hi*16) ^ ((lo & 7) << 4))) >> 1];
        __builtin_amdgcn_s_setprio(1);
        #pragma unroll
        for (int dj=0;dj<8;dj++){
          int row = dj*16 + lo;
          int cb0 = (hi*16)      ^ ((lo & 7) << 4);
          int cb1 = (64 + hi*16) ^ ((lo & 7) << 4);
          bf16x8 vv0 = *(const bf16x8*)&vcur[row*64 + (cb0 >> 1)];
          bf16x8 vv1 = *(const bf16x8*)&vcur[row*64 + (cb1 >> 1)];
          o[dj] = __builtin_amdgcn_mfma_f32_16x16x32_bf16(pa[0], vv0, o[dj], 0,0,0);
          o[dj] = __builtin_amdgcn_mfma_f32_16x16x32_bf16(pa[1], vv1, o[dj], 0,0,0);
        }
        __builtin_amdgcn_s_setprio(0);
      }
      __syncthreads();
    }

    #pragma unroll
    for (int r=0;r<4;r++){
      float inv = 1.0f / lsum[r];
      size_t row = (size_t)(b*2048 + qw + hi*4 + r);
      #pragma unroll
      for (int dj=0;dj<8;dj++)
        y[row*2048 + h*128 + dj*16 + lo] = f2bf(o[dj][r] * inv);
    }
    __syncthreads();
  }
}

extern "C" void kernel_launch(void* const* d_in, const int* in_sizes, int n_in,
                              void* d_out, int out_size, void* d_ws, size_t ws_size,
                              hipStream_t stream) {
  (void)in_sizes; (void)n_in; (void)out_size; (void)ws_size;
  const float* x      = (const float*)d_in[0];  // [8192][2048] f32
  const float* w_attn = (const float*)d_in[1];  // [2048][6144] f32
  const float* b_attn = (const float*)d_in[2];  // [6144] f32
  const float* w_proj = (const float*)d_in[3];  // [2048][2048] f32
  const float* b_proj = (const float*)d_in[4];  // [2048] f32
  float* out = (float*)d_out;                   // [8192][2048] f32

  char* ws = (char*)d_ws;
  u16* xbf = (u16*)(ws);                     // [8192][2048] bf16, 32 MB; reused as y
  u16* wT  = (u16*)(ws + 33554432);          // [6144][2048] bf16, 24 MB
  u16* pT  = (u16*)(ws + 58720256);          // [2048][2048] bf16,  8 MB
  u16* qkv = (u16*)(ws + 67108864);          // [8192][6144] bf16, 96 MB
  u16* vt  = (u16*)(ws + 167772160);         // [64][128][2048] bf16, 32 MB
  u16* y   = xbf;

  cvt_f2b<<<16384, 256, 0, stream>>>(x, xbf, 8192*2048);
  transpose2d_f2b<<<dim3(96,32), 256, 0, stream>>>(w_attn, wT, 2048, 6144);
  transpose2d_f2b<<<dim3(32,32), 256, 0, stream>>>(w_proj, pT, 2048, 2048);
  // QKV: 32 m-tiles x 24 n-tiles = 768 blocks
  gemm8p<0><<<768, 512, 0, stream>>>(xbf, wT, b_attn, qkv, 8192, 6144, 2048, 32);
  transpose_v<<<dim3(2,32,64), 256, 0, stream>>>(qkv, vt);
  attn_fwd<<<dim3(8,64), 512, 0, stream>>>(qkv, vt, y);
  // proj: 32 m-tiles x 8 n-tiles = 256 blocks
  gemm8p<1><<<256, 512, 0, stream>>>(y, pT, b_proj, out, 8192, 2048, 2048, 32);
}